// Round 6
// baseline (1023.766 us; speedup 1.0000x reference)
//
#include <hip/hip_runtime.h>
#include <hip/hip_bf16.h>
#include <math.h>

// TransformerBlock: B=4,S=1024,D=1024,H=16,DK=64,DFF=4096.
// Externals f32, OUTPUT f32 (reference dtype). Intermediates bf16 in ws.
// Pipeline: LN1 -> QKV gemms (scatter [B,H,S,DK]) -> attention -> wo gemm (+x) ->
//           LN2 -> w1 gemm (GELU) -> w2 gemm (+nx2) -> LN3 -> w3 gemm (+x1 +yb) -> f32 out.

constexpr int Bc = 4, Sc_ = 1024, Dc = 1024, Hc = 16, DKc = 64, DFFc = 4096;
constexpr int ROWS = Bc * Sc_;   // 4096

typedef short short8 __attribute__((ext_vector_type(8)));
typedef __bf16 bf16x8 __attribute__((ext_vector_type(8)));
typedef float float4v __attribute__((ext_vector_type(4)));

__device__ __forceinline__ float bf2f(ushort u) {
    union { uint i; float f; } v; v.i = ((uint)u) << 16; return v.f;
}
__device__ __forceinline__ ushort f2bf(float f) {
    union { float f; uint i; } v; v.f = f;
    uint r = v.i + 0x7FFF + ((v.i >> 16) & 1);   // RNE
    return (ushort)(r >> 16);
}
__device__ __forceinline__ bf16x8 as_bf(short8 s) {
    union { short8 s; bf16x8 b; } u; u.s = s; return u.b;
}

__global__ void sentinel_kernel(float* __restrict__ out, int n) {
    int i = blockIdx.x * 256 + threadIdx.x;
    if (i < n) out[i] = 100.0f;
}

// ---------------- LayerNorm: one block per row of D=1024 ----------------
template<bool IN_F32>
__global__ __launch_bounds__(256) void ln_kernel(const void* __restrict__ xin,
                                                 const float* __restrict__ g,
                                                 const float* __restrict__ be,
                                                 ushort* __restrict__ out) {
    int row = blockIdx.x;
    int tid = threadIdx.x;
    float v0[4], s = 0.f, ss = 0.f;
#pragma unroll
    for (int i = 0; i < 4; i++) {
        int c = tid + i * 256;
        float f = IN_F32 ? ((const float*)xin)[(size_t)row * Dc + c]
                         : bf2f(((const ushort*)xin)[(size_t)row * Dc + c]);
        v0[i] = f; s += f; ss += f * f;
    }
#pragma unroll
    for (int off = 32; off > 0; off >>= 1) {
        s += __shfl_down(s, off);
        ss += __shfl_down(ss, off);
    }
    __shared__ float red[8];
    __shared__ float stat[2];
    int wave = tid >> 6, lane = tid & 63;
    if (lane == 0) { red[wave] = s; red[wave + 4] = ss; }
    __syncthreads();
    if (tid == 0) {
        float a = 0.f, b = 0.f;
        for (int w = 0; w < 4; w++) { a += red[w]; b += red[w + 4]; }
        stat[0] = a; stat[1] = b;
    }
    __syncthreads();
    float mean = stat[0] * (1.f / Dc);
    float var  = stat[1] * (1.f / Dc) - mean * mean;
    float inv  = rsqrtf(var + 1e-5f);
#pragma unroll
    for (int i = 0; i < 4; i++) {
        int c = tid + i * 256;
        float nv = (v0[i] - mean) * inv * g[c] + be[c];
        out[(size_t)row * Dc + c] = f2bf(nv);
    }
}

// ---------------- GEMM: C = A[MxK](bf16) @ W[KxN](f32->bf16) + bias(f32) ----------------
constexpr int BM = 128, BN = 128, BK = 32;

template<typename OutT>
__global__ __launch_bounds__(256) void gemm_kernel(
    const ushort* __restrict__ Ag, const float* __restrict__ Wg,
    const float* __restrict__ biasg,
    const float* __restrict__ res1f,        // external f32 residual
    const ushort* __restrict__ resi1, const ushort* __restrict__ resi2,  // bf16 residuals
    OutT* __restrict__ outg,
    int M, int N, int K, int do_gelu, int scatter) {
    __shared__ ushort As[BM][BK + 8];   // row stride 40 shorts
    __shared__ ushort Ws[BK][BN + 8];   // row stride 136 shorts
    const int tid = threadIdx.x;
    const int wave = tid >> 6, lane = tid & 63;
    const int quad = lane >> 4, l16 = lane & 15;
    const int m0 = blockIdx.y * BM, n0 = blockIdx.x * BN;
    const int wm = (wave >> 1) * 64, wn = (wave & 1) * 64;

    float4v acc[4][4];
    const float4v zero = {0.f, 0.f, 0.f, 0.f};
#pragma unroll
    for (int i = 0; i < 4; i++)
#pragma unroll
        for (int j = 0; j < 4; j++) acc[i][j] = zero;

    const int ar = tid >> 2, ac = (tid & 3) * 8;
    const int wr = tid >> 4, wc = (tid & 15) * 8;

    for (int k0 = 0; k0 < K; k0 += BK) {
#pragma unroll
        for (int it = 0; it < 2; it++) {
            int row = ar + it * 64;
            short8 v = *reinterpret_cast<const short8*>(Ag + (size_t)(m0 + row) * K + k0 + ac);
            *reinterpret_cast<short8*>(&As[row][ac]) = v;
        }
#pragma unroll
        for (int it = 0; it < 2; it++) {
            int row = wr + it * 16;
            const float* src = Wg + (size_t)(k0 + row) * N + n0 + wc;
            float4v f0 = *reinterpret_cast<const float4v*>(src);
            float4v f1 = *reinterpret_cast<const float4v*>(src + 4);
            short8 v;
#pragma unroll
            for (int q = 0; q < 4; q++) { v[q] = (short)f2bf(f0[q]); v[q + 4] = (short)f2bf(f1[q]); }
            *reinterpret_cast<short8*>(&Ws[row][wc]) = v;
        }
        __syncthreads();
        short8 af[4];
#pragma unroll
        for (int i = 0; i < 4; i++)
            af[i] = *reinterpret_cast<const short8*>(&As[wm + i * 16 + l16][quad * 8]);
#pragma unroll
        for (int j = 0; j < 4; j++) {
            short8 bfr;
            int n = wn + j * 16 + l16;
#pragma unroll
            for (int jj = 0; jj < 8; jj++) bfr[jj] = (short)Ws[quad * 8 + jj][n];
#pragma unroll
            for (int i = 0; i < 4; i++)
                acc[i][j] = __builtin_amdgcn_mfma_f32_16x16x32_bf16(as_bf(af[i]), as_bf(bfr), acc[i][j], 0, 0, 0);
        }
        __syncthreads();
    }
    // epilogue: C/D layout col=lane&15, row=quad*4+reg
#pragma unroll
    for (int j = 0; j < 4; j++) {
        int cg = n0 + wn + j * 16 + l16;
        float bv = biasg ? biasg[cg] : 0.f;
#pragma unroll
        for (int i = 0; i < 4; i++) {
#pragma unroll
            for (int r = 0; r < 4; r++) {
                int rg = m0 + wm + i * 16 + quad * 4 + r;
                float v = acc[i][j][r] + bv;
                if (do_gelu) v = 0.5f * v * (1.f + erff(v * 0.70710678118654752f));
                size_t idx = (size_t)rg * N + cg;
                if (res1f) v += res1f[idx];
                if (resi1) v += bf2f(resi1[idx]);
                if (resi2) v += bf2f(resi2[idx]);
                size_t dst;
                if (scatter) {   // [B*S, D] -> [B,H,S,DK]
                    int b = rg >> 10, s = rg & 1023;
                    int h = cg >> 6, dk = cg & 63;
                    dst = (((size_t)b * Hc + h) * Sc_ + s) * DKc + dk;
                } else dst = idx;
                if constexpr (sizeof(OutT) == 4) outg[dst] = v;
                else                             outg[dst] = f2bf(v);
            }
        }
    }
}

// ---------------- Attention: one block per (b,h, 16 Q rows) ----------------
__global__ __launch_bounds__(256) void attn_kernel(
    const ushort* __restrict__ Qg, const ushort* __restrict__ Kg,
    const ushort* __restrict__ Vg, const float* __restrict__ relg,
    ushort* __restrict__ ctxg) {
    __shared__ ushort Sl[16][Sc_ + 8];     // logits -> P (bf16)
    __shared__ ushort Qs[16][DKc + 8];
    __shared__ ushort Vs[32][DKc + 8];
    __shared__ float red[16][16];
    __shared__ float rowmax[16], rowinv[16];

    const int blk = blockIdx.x;
    const int qt = blk & 63;
    const int bh = blk >> 6;
    const int h = bh & (Hc - 1);
    const int b = bh >> 4;
    const int tid = threadIdx.x;
    const int wave = tid >> 6, lane = tid & 63;
    const int quad = lane >> 4, l16 = lane & 15;

    if (tid < 128) {
        int r = tid >> 3, c = (tid & 7) * 8;
        short8 v = *reinterpret_cast<const short8*>(
            Qg + ((size_t)bh * Sc_ + qt * 16 + r) * DKc + c);
        *reinterpret_cast<short8*>(&Qs[r][c]) = v;
    }
    __syncthreads();

    short8 aQ[2];
#pragma unroll
    for (int f = 0; f < 2; f++)
        aQ[f] = *reinterpret_cast<const short8*>(&Qs[l16][f * 32 + quad * 8]);

    // pass A: logits = Q K^T / 8 + relbias  -> LDS (bf16)
    for (int i = 0; i < 16; i++) {
        int nt = wave + i * 4;
        int t = nt * 16 + l16;
        float4v acc = {0.f, 0.f, 0.f, 0.f};
#pragma unroll
        for (int f = 0; f < 2; f++) {
            short8 bK = *reinterpret_cast<const short8*>(
                Kg + ((size_t)bh * Sc_ + t) * DKc + f * 32 + quad * 8);
            acc = __builtin_amdgcn_mfma_f32_16x16x32_bf16(as_bf(aQ[f]), as_bf(bK), acc, 0, 0, 0);
        }
#pragma unroll
        for (int r = 0; r < 4; r++) {
            int srow = quad * 4 + r;
            int sg = qt * 16 + srow;
            int rel = min(max(t - sg + 63, 0), 126);
            float bias = relg[rel * Hc + h];
            Sl[srow][t] = f2bf(acc[r] * 0.125f + bias);
        }
    }
    __syncthreads();

    // softmax over full row (S=1024) in LDS
    {
        int row = tid >> 4, j = tid & 15;
        float mx = -1e30f;
        for (int i = 0; i < 64; i++) mx = fmaxf(mx, bf2f(Sl[row][j + 16 * i]));
        red[row][j] = mx;
        __syncthreads();
        if (tid < 16) {
            float m = -1e30f;
            for (int k = 0; k < 16; k++) m = fmaxf(m, red[tid][k]);
            rowmax[tid] = m;
        }
        __syncthreads();
        float rm = rowmax[row];
        float sum = 0.f;
        for (int i = 0; i < 64; i++) {
            int c = j + 16 * i;
            float e = expf(bf2f(Sl[row][c]) - rm);
            sum += e;
            Sl[row][c] = f2bf(e);
        }
        red[row][j] = sum;
        __syncthreads();
        if (tid < 16) {
            float sm = 0.f;
            for (int k = 0; k < 16; k++) sm += red[tid][k];
            rowinv[tid] = 1.f / sm;
        }
        __syncthreads();
    }

    // pass B: ctx = P @ V, normalize in epilogue
    float4v accO = {0.f, 0.f, 0.f, 0.f};
    const int d = wave * 16 + l16;
    for (int t0 = 0; t0 < Sc_; t0 += 32) {
        __syncthreads();
        {
            int r = tid >> 3, c = (tid & 7) * 8;
            short8 v = *reinterpret_cast<const short8*>(
                Vg + ((size_t)bh * Sc_ + t0 + r) * DKc + c);
            *reinterpret_cast<short8*>(&Vs[r][c]) = v;
        }
        __syncthreads();
        short8 aP = *reinterpret_cast<const short8*>(&Sl[l16][t0 + quad * 8]);
        short8 bV;
#pragma unroll
        for (int jj = 0; jj < 8; jj++) bV[jj] = (short)Vs[quad * 8 + jj][d];
        accO = __builtin_amdgcn_mfma_f32_16x16x32_bf16(as_bf(aP), as_bf(bV), accO, 0, 0, 0);
    }
#pragma unroll
    for (int r = 0; r < 4; r++) {
        int srow = quad * 4 + r;
        float v = accO[r] * rowinv[srow];
        int s = qt * 16 + srow;
        ctxg[((size_t)b * Sc_ + s) * Dc + h * DKc + d] = f2bf(v);
    }
}

extern "C" void kernel_launch(void* const* d_in, const int* in_sizes, int n_in,
                              void* d_out, int out_size, void* d_ws, size_t ws_size,
                              hipStream_t stream) {
    float* out = (float*)d_out;

    static const int exp_sizes[22] = {
        4194304, 1048576, 1024, 1048576, 1024, 1048576, 1024, 1048576, 1024,
        2032, 1024, 1024, 1024, 1024, 4194304, 4096, 4194304, 1024,
        1048576, 1024, 1024, 1024};
    bool ok = (n_in == 22);
    if (ok) for (int i = 0; i < 22; i++) if (in_sizes[i] != exp_sizes[i]) { ok = false; break; }
    if (!ok) {
        sentinel_kernel<<<(out_size + 255) / 256, 256, 0, stream>>>(out, out_size);
        return;
    }

    const float* x   = (const float*)d_in[0];
    const float* wq  = (const float*)d_in[1];  const float* bq  = (const float*)d_in[2];
    const float* wk  = (const float*)d_in[3];  const float* bk  = (const float*)d_in[4];
    const float* wv  = (const float*)d_in[5];  const float* bv  = (const float*)d_in[6];
    const float* wo  = (const float*)d_in[7];  const float* bo  = (const float*)d_in[8];
    const float* rel = (const float*)d_in[9];
    const float* g1  = (const float*)d_in[10]; const float* be1 = (const float*)d_in[11];
    const float* g2  = (const float*)d_in[12]; const float* be2 = (const float*)d_in[13];
    const float* w1  = (const float*)d_in[14]; const float* b1  = (const float*)d_in[15];
    const float* w2  = (const float*)d_in[16]; const float* b2  = (const float*)d_in[17];
    const float* w3  = (const float*)d_in[18]; const float* b3  = (const float*)d_in[19];
    const float* gf  = (const float*)d_in[20]; const float* bfp = (const float*)d_in[21];

    // ws: bf16 buffers, 64 MiB with reuse
    constexpr size_t NE = (size_t)ROWS * Dc;   // 4M elements
    ushort* base = (ushort*)d_ws;
    ushort* nx  = base;               // [0, 4M)
    ushort* Qb  = base + NE;          // [4M, 8M)
    ushort* Kb  = base + 2 * NE;      // [8M, 12M)
    ushort* Vb  = base + 3 * NE;      // [12M, 16M)
    ushort* ctx = base;               // reuse nx (dead after QKV gemms)
    ushort* x1  = base + NE;          // reuse Qb (dead after attn)
    ushort* nx2 = base + 2 * NE;      // reuse Kb (dead after attn)
    ushort* hb  = base + 3 * NE;      // [12M, 28M) reuse Vb (dead after attn)
    ushort* yb  = base + 7 * NE;      // [28M, 32M)
    ushort* ly  = base;               // reuse ctx (dead after wo gemm)

    dim3 blk(256);
    dim3 gD(Dc / BN, ROWS / BM);       // (8, 32)
    dim3 gFF(DFFc / BN, ROWS / BM);    // (32, 32)

    ln_kernel<true><<<ROWS, blk, 0, stream>>>(x, g1, be1, nx);
    gemm_kernel<ushort><<<gD, blk, 0, stream>>>(nx, wq, bq, nullptr, nullptr, nullptr, Qb, ROWS, Dc, Dc, 0, 1);
    gemm_kernel<ushort><<<gD, blk, 0, stream>>>(nx, wk, bk, nullptr, nullptr, nullptr, Kb, ROWS, Dc, Dc, 0, 1);
    gemm_kernel<ushort><<<gD, blk, 0, stream>>>(nx, wv, bv, nullptr, nullptr, nullptr, Vb, ROWS, Dc, Dc, 0, 1);
    attn_kernel<<<ROWS, blk, 0, stream>>>(Qb, Kb, Vb, rel, ctx);
    gemm_kernel<ushort><<<gD, blk, 0, stream>>>(ctx, wo, bo, x, nullptr, nullptr, x1, ROWS, Dc, Dc, 0, 0);
    ln_kernel<false><<<ROWS, blk, 0, stream>>>(x1, g2, be2, nx2);
    gemm_kernel<ushort><<<gFF, blk, 0, stream>>>(nx2, w1, b1, nullptr, nullptr, nullptr, hb, ROWS, DFFc, Dc, 1, 0);
    gemm_kernel<ushort><<<gD, blk, 0, stream>>>(hb, w2, b2, nullptr, nx2, nullptr, yb, ROWS, Dc, DFFc, 0, 0);
    ln_kernel<false><<<ROWS, blk, 0, stream>>>(yb, gf, bfp, ly);
    gemm_kernel<float><<<gD, blk, 0, stream>>>(ly, w3, b3, nullptr, x1, yb, out, ROWS, Dc, Dc, 0, 0);
}

// Round 7
// 761.376 us; speedup vs baseline: 1.3446x; 1.3446x over previous
//
#include <hip/hip_runtime.h>
#include <hip/hip_bf16.h>
#include <math.h>

// TransformerBlock B=4,S=1024,D=1024,H=16,DK=64,DFF=4096. Externals f32, out f32.
// GEMMs: per-matrix transpose+convert pass (W[K][N] f32 -> Wt[N][K] bf16, 8MB scratch),
// then m97-style bt-GEMM: global_load_lds(16B) staging, ds_read_b128 fragments.

constexpr int Bc = 4, Sc_ = 1024, Dc = 1024, Hc = 16, DKc = 64, DFFc = 4096;
constexpr int ROWS = Bc * Sc_;   // 4096

typedef short short8 __attribute__((ext_vector_type(8)));
typedef __bf16 bf16x8 __attribute__((ext_vector_type(8)));
typedef float float4v __attribute__((ext_vector_type(4)));

__device__ __forceinline__ float bf2f(ushort u) {
    union { uint i; float f; } v; v.i = ((uint)u) << 16; return v.f;
}
__device__ __forceinline__ ushort f2bf(float f) {
    union { float f; uint i; } v; v.f = f;
    uint r = v.i + 0x7FFF + ((v.i >> 16) & 1);   // RNE
    return (ushort)(r >> 16);
}
__device__ __forceinline__ bf16x8 as_bf(short8 s) {
    union { short8 s; bf16x8 b; } u; u.s = s; return u.b;
}
__device__ __forceinline__ void async_copy16(void* lds, const void* g) {
    __builtin_amdgcn_global_load_lds((const __attribute__((address_space(1))) uint*)g,
                                     (__attribute__((address_space(3))) uint*)lds, 16, 0, 0);
}

__global__ void sentinel_kernel(float* __restrict__ out, int n) {
    int i = blockIdx.x * 256 + threadIdx.x;
    if (i < n) out[i] = 100.0f;
}

// ---- transpose+convert: W[K][N] f32 -> Wt[N][K] bf16, 64x64 tiles ----
__global__ __launch_bounds__(256) void wconv_kernel(const float* __restrict__ W,
                                                    ushort* __restrict__ Wt,
                                                    int K, int N) {
    __shared__ float T[64][65];
    const int kt = blockIdx.y * 64, nt = blockIdx.x * 64;
    const int tid = threadIdx.x;
#pragma unroll
    for (int it = 0; it < 4; it++) {
        int r = it * 16 + (tid >> 4), c = (tid & 15) * 4;
        float4v v = *reinterpret_cast<const float4v*>(W + (size_t)(kt + r) * N + nt + c);
        T[r][c] = v[0]; T[r][c + 1] = v[1]; T[r][c + 2] = v[2]; T[r][c + 3] = v[3];
    }
    __syncthreads();
    int n = tid >> 2, kc = (tid & 3) * 16;
    short8 a, b;
#pragma unroll
    for (int q = 0; q < 8; q++) {
        a[q] = (short)f2bf(T[kc + q][n]);
        b[q] = (short)f2bf(T[kc + 8 + q][n]);
    }
    ushort* dst = Wt + (size_t)(nt + n) * K + kt + kc;
    *reinterpret_cast<short8*>(dst) = a;
    *reinterpret_cast<short8*>(dst + 8) = b;
}

// ---- LayerNorm: one block per row of D=1024 ----
template<bool IN_F32>
__global__ __launch_bounds__(256) void ln_kernel(const void* __restrict__ xin,
                                                 const float* __restrict__ g,
                                                 const float* __restrict__ be,
                                                 ushort* __restrict__ out) {
    int row = blockIdx.x;
    int tid = threadIdx.x;
    float v0[4], s = 0.f, ss = 0.f;
#pragma unroll
    for (int i = 0; i < 4; i++) {
        int c = tid + i * 256;
        float f = IN_F32 ? ((const float*)xin)[(size_t)row * Dc + c]
                         : bf2f(((const ushort*)xin)[(size_t)row * Dc + c]);
        v0[i] = f; s += f; ss += f * f;
    }
#pragma unroll
    for (int off = 32; off > 0; off >>= 1) {
        s += __shfl_down(s, off);
        ss += __shfl_down(ss, off);
    }
    __shared__ float red[8];
    __shared__ float stat[2];
    int wave = tid >> 6, lane = tid & 63;
    if (lane == 0) { red[wave] = s; red[wave + 4] = ss; }
    __syncthreads();
    if (tid == 0) {
        float a = 0.f, b = 0.f;
        for (int w = 0; w < 4; w++) { a += red[w]; b += red[w + 4]; }
        stat[0] = a; stat[1] = b;
    }
    __syncthreads();
    float mean = stat[0] * (1.f / Dc);
    float var  = stat[1] * (1.f / Dc) - mean * mean;
    float inv  = rsqrtf(var + 1e-5f);
#pragma unroll
    for (int i = 0; i < 4; i++) {
        int c = tid + i * 256;
        float nv = (v0[i] - mean) * inv * g[c] + be[c];
        out[(size_t)row * Dc + c] = f2bf(nv);
    }
}

// ---- bt-GEMM: C[M][N] = A[M][K](bf16) @ Wt[N][K]^T(bf16) + bias(f32), fused epilogue ----
constexpr int BM = 128, BN = 128, BK = 32;

template<typename OutT>
__global__ __launch_bounds__(256) void gemm_bt(
    const ushort* __restrict__ Ag, const ushort* __restrict__ Wt,
    const float* __restrict__ biasg,
    const float* __restrict__ res1f,
    const ushort* __restrict__ resi1, const ushort* __restrict__ resi2,
    OutT* __restrict__ outg,
    int M, int N, int K, int do_gelu, int scatter) {
    __shared__ ushort As[BM * BK];   // [row][32] unpadded (global_load_lds layout)
    __shared__ ushort Bs[BN * BK];   // Wt rows: [n][32]
    const int tid = threadIdx.x;
    const int wave = tid >> 6, lane = tid & 63;
    const int quad = lane >> 4, l16 = lane & 15;
    const int m0 = blockIdx.y * BM, n0 = blockIdx.x * BN;
    const int wm = (wave >> 1) * 64, wn = (wave & 1) * 64;

    float4v acc[4][4];
    const float4v zero = {0.f, 0.f, 0.f, 0.f};
#pragma unroll
    for (int i = 0; i < 4; i++)
#pragma unroll
        for (int j = 0; j < 4; j++) acc[i][j] = zero;

    const int sr = tid >> 2;             // 0..63 row-within-64
    const int sc = (tid & 3) * 8;        // k-chunk
    const int ldsoff = (tid >> 6) * 512; // wave*512 shorts within 64-row segment

    for (int k0 = 0; k0 < K; k0 += BK) {
#pragma unroll
        for (int it = 0; it < 2; it++) {
            async_copy16(&As[it * 2048 + ldsoff],
                         Ag + (size_t)(m0 + it * 64 + sr) * K + k0 + sc);
            async_copy16(&Bs[it * 2048 + ldsoff],
                         Wt + (size_t)(n0 + it * 64 + sr) * K + k0 + sc);
        }
        __syncthreads();   // drains vmcnt -> LDS tiles complete
        short8 af[4], bfr[4];
#pragma unroll
        for (int i = 0; i < 4; i++)
            af[i] = *reinterpret_cast<const short8*>(&As[(wm + i * 16 + l16) * BK + quad * 8]);
#pragma unroll
        for (int j = 0; j < 4; j++)
            bfr[j] = *reinterpret_cast<const short8*>(&Bs[(wn + j * 16 + l16) * BK + quad * 8]);
#pragma unroll
        for (int j = 0; j < 4; j++)
#pragma unroll
            for (int i = 0; i < 4; i++)
                acc[i][j] = __builtin_amdgcn_mfma_f32_16x16x32_bf16(as_bf(af[i]), as_bf(bfr[j]), acc[i][j], 0, 0, 0);
        __syncthreads();
    }
    // epilogue: C/D layout col=lane&15, row=quad*4+reg
#pragma unroll
    for (int j = 0; j < 4; j++) {
        int cg = n0 + wn + j * 16 + l16;
        float bv = biasg ? biasg[cg] : 0.f;
#pragma unroll
        for (int i = 0; i < 4; i++) {
#pragma unroll
            for (int r = 0; r < 4; r++) {
                int rg = m0 + wm + i * 16 + quad * 4 + r;
                float v = acc[i][j][r] + bv;
                if (do_gelu) v = 0.5f * v * (1.f + erff(v * 0.70710678118654752f));
                size_t idx = (size_t)rg * N + cg;
                if (res1f) v += res1f[idx];
                if (resi1) v += bf2f(resi1[idx]);
                if (resi2) v += bf2f(resi2[idx]);
                size_t dst;
                if (scatter) {   // [B*S, D] -> [B,H,S,DK]
                    int b = rg >> 10, s = rg & 1023;
                    int h = cg >> 6, dk = cg & 63;
                    dst = (((size_t)b * Hc + h) * Sc_ + s) * DKc + dk;
                } else dst = idx;
                if constexpr (sizeof(OutT) == 4) outg[dst] = v;
                else                             outg[dst] = f2bf(v);
            }
        }
    }
}

// ---- Attention: one block per (b,h, 16 Q rows) ----
__global__ __launch_bounds__(256) void attn_kernel(
    const ushort* __restrict__ Qg, const ushort* __restrict__ Kg,
    const ushort* __restrict__ Vg, const float* __restrict__ relg,
    ushort* __restrict__ ctxg) {
    __shared__ ushort Sl[16][Sc_ + 8];
    __shared__ ushort Qs[16][DKc + 8];
    __shared__ ushort Vs[32][DKc + 8];
    __shared__ float red[16][16];
    __shared__ float rowmax[16], rowinv[16];

    const int blk = blockIdx.x;
    const int qt = blk & 63;
    const int bh = blk >> 6;
    const int h = bh & (Hc - 1);
    const int b = bh >> 4;
    const int tid = threadIdx.x;
    const int wave = tid >> 6, lane = tid & 63;
    const int quad = lane >> 4, l16 = lane & 15;

    if (tid < 128) {
        int r = tid >> 3, c = (tid & 7) * 8;
        short8 v = *reinterpret_cast<const short8*>(
            Qg + ((size_t)bh * Sc_ + qt * 16 + r) * DKc + c);
        *reinterpret_cast<short8*>(&Qs[r][c]) = v;
    }
    __syncthreads();

    short8 aQ[2];
#pragma unroll
    for (int f = 0; f < 2; f++)
        aQ[f] = *reinterpret_cast<const short8*>(&Qs[l16][f * 32 + quad * 8]);

    for (int i = 0; i < 16; i++) {
        int nt = wave + i * 4;
        int t = nt * 16 + l16;
        float4v acc = {0.f, 0.f, 0.f, 0.f};
#pragma unroll
        for (int f = 0; f < 2; f++) {
            short8 bK = *reinterpret_cast<const short8*>(
                Kg + ((size_t)bh * Sc_ + t) * DKc + f * 32 + quad * 8);
            acc = __builtin_amdgcn_mfma_f32_16x16x32_bf16(as_bf(aQ[f]), as_bf(bK), acc, 0, 0, 0);
        }
#pragma unroll
        for (int r = 0; r < 4; r++) {
            int srow = quad * 4 + r;
            int sg = qt * 16 + srow;
            int rel = min(max(t - sg + 63, 0), 126);
            float bias = relg[rel * Hc + h];
            Sl[srow][t] = f2bf(acc[r] * 0.125f + bias);
        }
    }
    __syncthreads();

    {
        int row = tid >> 4, j = tid & 15;
        float mx = -1e30f;
        for (int i = 0; i < 64; i++) mx = fmaxf(mx, bf2f(Sl[row][j + 16 * i]));
        red[row][j] = mx;
        __syncthreads();
        if (tid < 16) {
            float m = -1e30f;
            for (int k = 0; k < 16; k++) m = fmaxf(m, red[tid][k]);
            rowmax[tid] = m;
        }
        __syncthreads();
        float rm = rowmax[row];
        float sum = 0.f;
        for (int i = 0; i < 64; i++) {
            int c = j + 16 * i;
            float e = expf(bf2f(Sl[row][c]) - rm);
            sum += e;
            Sl[row][c] = f2bf(e);
        }
        red[row][j] = sum;
        __syncthreads();
        if (tid < 16) {
            float sm = 0.f;
            for (int k = 0; k < 16; k++) sm += red[tid][k];
            rowinv[tid] = 1.f / sm;
        }
        __syncthreads();
    }

    float4v accO = {0.f, 0.f, 0.f, 0.f};
    const int d = wave * 16 + l16;
    for (int t0 = 0; t0 < Sc_; t0 += 32) {
        __syncthreads();
        {
            int r = tid >> 3, c = (tid & 7) * 8;
            short8 v = *reinterpret_cast<const short8*>(
                Vg + ((size_t)bh * Sc_ + t0 + r) * DKc + c);
            *reinterpret_cast<short8*>(&Vs[r][c]) = v;
        }
        __syncthreads();
        short8 aP = *reinterpret_cast<const short8*>(&Sl[l16][t0 + quad * 8]);
        short8 bV;
#pragma unroll
        for (int jj = 0; jj < 8; jj++) bV[jj] = (short)Vs[quad * 8 + jj][d];
        accO = __builtin_amdgcn_mfma_f32_16x16x32_bf16(as_bf(aP), as_bf(bV), accO, 0, 0, 0);
    }
#pragma unroll
    for (int r = 0; r < 4; r++) {
        int srow = quad * 4 + r;
        float v = accO[r] * rowinv[srow];
        int s = qt * 16 + srow;
        ctxg[((size_t)b * Sc_ + s) * Dc + h * DKc + d] = f2bf(v);
    }
}

extern "C" void kernel_launch(void* const* d_in, const int* in_sizes, int n_in,
                              void* d_out, int out_size, void* d_ws, size_t ws_size,
                              hipStream_t stream) {
    float* out = (float*)d_out;

    static const int exp_sizes[22] = {
        4194304, 1048576, 1024, 1048576, 1024, 1048576, 1024, 1048576, 1024,
        2032, 1024, 1024, 1024, 1024, 4194304, 4096, 4194304, 1024,
        1048576, 1024, 1024, 1024};
    bool ok = (n_in == 22);
    if (ok) for (int i = 0; i < 22; i++) if (in_sizes[i] != exp_sizes[i]) { ok = false; break; }
    if (!ok) {
        sentinel_kernel<<<(out_size + 255) / 256, 256, 0, stream>>>(out, out_size);
        return;
    }

    const float* x   = (const float*)d_in[0];
    const float* wq  = (const float*)d_in[1];  const float* bq  = (const float*)d_in[2];
    const float* wk  = (const float*)d_in[3];  const float* bk  = (const float*)d_in[4];
    const float* wv  = (const float*)d_in[5];  const float* bv  = (const float*)d_in[6];
    const float* wo  = (const float*)d_in[7];  const float* bo  = (const float*)d_in[8];
    const float* rel = (const float*)d_in[9];
    const float* g1  = (const float*)d_in[10]; const float* be1 = (const float*)d_in[11];
    const float* g2  = (const float*)d_in[12]; const float* be2 = (const float*)d_in[13];
    const float* w1  = (const float*)d_in[14]; const float* b1  = (const float*)d_in[15];
    const float* w2  = (const float*)d_in[16]; const float* b2  = (const float*)d_in[17];
    const float* w3  = (const float*)d_in[18]; const float* b3  = (const float*)d_in[19];
    const float* gf  = (const float*)d_in[20]; const float* bfp = (const float*)d_in[21];

    // ws (64 MiB = 8*NE shorts): [Wt scratch NE][act buffers 7*NE with reuse]
    constexpr size_t NE = (size_t)ROWS * Dc;   // 4M elements
    ushort* base = (ushort*)d_ws;
    ushort* Wts = base;               // weight scratch [0,NE) (w1/w2 use all of it)
    ushort* nx  = base + NE;          // [NE,2NE)
    ushort* Qb  = base + 2 * NE;
    ushort* Kb  = base + 3 * NE;
    ushort* Vb  = base + 4 * NE;
    ushort* ctx = nx;                 // reuse nx (dead after QKV gemms)
    ushort* x1  = Qb;                 // reuse Qb (dead after attn)
    ushort* nx2 = Kb;                 // reuse Kb (dead after attn)
    ushort* hb  = base + 4 * NE;      // [4NE,8NE): reuse Vb (dead after attn) + tail
    ushort* yb  = nx;                 // reuse ctx (dead after wo gemm)
    ushort* ly  = Kb;                 // reuse nx2 (dead after w2 gemm)

    dim3 blk(256);
    dim3 gD(Dc / BN, ROWS / BM);       // (8, 32)
    dim3 gFF(DFFc / BN, ROWS / BM);    // (32, 32)
    dim3 cD(Dc / 64, Dc / 64);         // (16,16)
    dim3 c1(DFFc / 64, Dc / 64);       // (64,16)
    dim3 c2(Dc / 64, DFFc / 64);       // (16,64)

    ln_kernel<true><<<ROWS, blk, 0, stream>>>(x, g1, be1, nx);
    wconv_kernel<<<cD, blk, 0, stream>>>(wq, Wts, Dc, Dc);
    gemm_bt<ushort><<<gD, blk, 0, stream>>>(nx, Wts, bq, nullptr, nullptr, nullptr, Qb, ROWS, Dc, Dc, 0, 1);
    wconv_kernel<<<cD, blk, 0, stream>>>(wk, Wts, Dc, Dc);
    gemm_bt<ushort><<<gD, blk, 0, stream>>>(nx, Wts, bk, nullptr, nullptr, nullptr, Kb, ROWS, Dc, Dc, 0, 1);
    wconv_kernel<<<cD, blk, 0, stream>>>(wv, Wts, Dc, Dc);
    gemm_bt<ushort><<<gD, blk, 0, stream>>>(nx, Wts, bv, nullptr, nullptr, nullptr, Vb, ROWS, Dc, Dc, 0, 1);
    attn_kernel<<<ROWS, blk, 0, stream>>>(Qb, Kb, Vb, rel, ctx);
    wconv_kernel<<<cD, blk, 0, stream>>>(wo, Wts, Dc, Dc);
    gemm_bt<ushort><<<gD, blk, 0, stream>>>(ctx, Wts, bo, x, nullptr, nullptr, x1, ROWS, Dc, Dc, 0, 0);
    ln_kernel<false><<<ROWS, blk, 0, stream>>>(x1, g2, be2, nx2);
    wconv_kernel<<<c1, blk, 0, stream>>>(w1, Wts, Dc, DFFc);
    gemm_bt<ushort><<<gFF, blk, 0, stream>>>(nx2, Wts, b1, nullptr, nullptr, nullptr, hb, ROWS, DFFc, Dc, 1, 0);
    wconv_kernel<<<c2, blk, 0, stream>>>(w2, Wts, DFFc, Dc);
    gemm_bt<ushort><<<gD, blk, 0, stream>>>(hb, Wts, b2, nullptr, nx2, nullptr, yb, ROWS, Dc, DFFc, 0, 0);
    ln_kernel<false><<<ROWS, blk, 0, stream>>>(yb, gf, bfp, ly);
    wconv_kernel<<<cD, blk, 0, stream>>>(w3, Wts, Dc, Dc);
    gemm_bt<float><<<gD, blk, 0, stream>>>(ly, Wts, b3, nullptr, x1, yb, out, ROWS, Dc, Dc, 0, 0);
}

// Round 8
// 749.361 us; speedup vs baseline: 1.3662x; 1.0160x over previous
//
#include <hip/hip_runtime.h>
#include <hip/hip_bf16.h>
#include <math.h>

// TransformerBlock B=4,S=1024,D=1024,H=16,DK=64,DFF=4096. Externals f32, out f32.
// GEMMs: wconv (W f32 -> Wt[N][K] bf16) + m97-style bt-GEMM (global_load_lds 16B,
// ds_read_b128 fragments), templated tile <BM,BN>. Attention: scores in LDS bf16,
// PV reads V from pre-transposed Vt[b,h,dk,s] directly from global (no barriers).

constexpr int Bc = 4, Sc_ = 1024, Dc = 1024, Hc = 16, DKc = 64, DFFc = 4096;
constexpr int ROWS = Bc * Sc_;   // 4096

typedef short short8 __attribute__((ext_vector_type(8)));
typedef __bf16 bf16x8 __attribute__((ext_vector_type(8)));
typedef float float4v __attribute__((ext_vector_type(4)));

__device__ __forceinline__ float bf2f(ushort u) {
    union { uint i; float f; } v; v.i = ((uint)u) << 16; return v.f;
}
__device__ __forceinline__ ushort f2bf(float f) {
    union { float f; uint i; } v; v.f = f;
    uint r = v.i + 0x7FFF + ((v.i >> 16) & 1);   // RNE
    return (ushort)(r >> 16);
}
__device__ __forceinline__ bf16x8 as_bf(short8 s) {
    union { short8 s; bf16x8 b; } u; u.s = s; return u.b;
}
__device__ __forceinline__ void async_copy16(void* lds, const void* g) {
    __builtin_amdgcn_global_load_lds((const __attribute__((address_space(1))) uint*)g,
                                     (__attribute__((address_space(3))) uint*)lds, 16, 0, 0);
}

__global__ void sentinel_kernel(float* __restrict__ out, int n) {
    int i = blockIdx.x * 256 + threadIdx.x;
    if (i < n) out[i] = 100.0f;
}

// ---- transpose+convert: W[K][N] f32 -> Wt[N][K] bf16, 64x64 tiles ----
__global__ __launch_bounds__(256) void wconv_kernel(const float* __restrict__ W,
                                                    ushort* __restrict__ Wt,
                                                    int K, int N) {
    __shared__ float T[64][65];
    const int kt = blockIdx.y * 64, nt = blockIdx.x * 64;
    const int tid = threadIdx.x;
#pragma unroll
    for (int it = 0; it < 4; it++) {
        int r = it * 16 + (tid >> 4), c = (tid & 15) * 4;
        float4v v = *reinterpret_cast<const float4v*>(W + (size_t)(kt + r) * N + nt + c);
        T[r][c] = v[0]; T[r][c + 1] = v[1]; T[r][c + 2] = v[2]; T[r][c + 3] = v[3];
    }
    __syncthreads();
    int n = tid >> 2, kc = (tid & 3) * 16;
    short8 a, b;
#pragma unroll
    for (int q = 0; q < 8; q++) {
        a[q] = (short)f2bf(T[kc + q][n]);
        b[q] = (short)f2bf(T[kc + 8 + q][n]);
    }
    ushort* dst = Wt + (size_t)(nt + n) * K + kt + kc;
    *reinterpret_cast<short8*>(dst) = a;
    *reinterpret_cast<short8*>(dst + 8) = b;
}

// ---- V transpose: V[b,h,s,dk] bf16 -> Vt[b,h,dk,s] bf16 ----
__global__ __launch_bounds__(256) void vconv_kernel(const ushort* __restrict__ V,
                                                    ushort* __restrict__ Vt) {
    __shared__ ushort T[64][65];   // stride 65: scalar column reads are 2-way (free)
    const int bh = blockIdx.y;
    const int s0 = blockIdx.x * 64;
    const int tid = threadIdx.x;
    const int r = tid >> 2, c = (tid & 3) * 16;
    const ushort* src = V + ((size_t)bh * Sc_ + s0 + r) * DKc + c;
    short8 a = *reinterpret_cast<const short8*>(src);
    short8 b = *reinterpret_cast<const short8*>(src + 8);
#pragma unroll
    for (int q = 0; q < 8; q++) { T[r][c + q] = (ushort)a[q]; T[r][c + 8 + q] = (ushort)b[q]; }
    __syncthreads();
    const int dk = tid >> 2, sc2 = (tid & 3) * 16;
    short8 o0, o1;
#pragma unroll
    for (int q = 0; q < 8; q++) { o0[q] = (short)T[sc2 + q][dk]; o1[q] = (short)T[sc2 + 8 + q][dk]; }
    ushort* dst = Vt + ((size_t)bh * DKc + dk) * Sc_ + s0 + sc2;
    *reinterpret_cast<short8*>(dst) = o0;
    *reinterpret_cast<short8*>(dst + 8) = o1;
}

// ---- LayerNorm: one block per row of D=1024 ----
template<bool IN_F32>
__global__ __launch_bounds__(256) void ln_kernel(const void* __restrict__ xin,
                                                 const float* __restrict__ g,
                                                 const float* __restrict__ be,
                                                 ushort* __restrict__ out) {
    int row = blockIdx.x;
    int tid = threadIdx.x;
    float v0[4], s = 0.f, ss = 0.f;
#pragma unroll
    for (int i = 0; i < 4; i++) {
        int c = tid + i * 256;
        float f = IN_F32 ? ((const float*)xin)[(size_t)row * Dc + c]
                         : bf2f(((const ushort*)xin)[(size_t)row * Dc + c]);
        v0[i] = f; s += f; ss += f * f;
    }
#pragma unroll
    for (int off = 32; off > 0; off >>= 1) {
        s += __shfl_down(s, off);
        ss += __shfl_down(ss, off);
    }
    __shared__ float red[8];
    __shared__ float stat[2];
    int wave = tid >> 6, lane = tid & 63;
    if (lane == 0) { red[wave] = s; red[wave + 4] = ss; }
    __syncthreads();
    if (tid == 0) {
        float a = 0.f, b = 0.f;
        for (int w = 0; w < 4; w++) { a += red[w]; b += red[w + 4]; }
        stat[0] = a; stat[1] = b;
    }
    __syncthreads();
    float mean = stat[0] * (1.f / Dc);
    float var  = stat[1] * (1.f / Dc) - mean * mean;
    float inv  = rsqrtf(var + 1e-5f);
#pragma unroll
    for (int i = 0; i < 4; i++) {
        int c = tid + i * 256;
        float nv = (v0[i] - mean) * inv * g[c] + be[c];
        out[(size_t)row * Dc + c] = f2bf(nv);
    }
}

// ---- bt-GEMM: C[M][N] = A[M][K](bf16) @ Wt[N][K]^T + bias(f32), fused epilogue ----
constexpr int BK = 32;

template<int BM, int BN, typename OutT>
__global__ __launch_bounds__((BM / 64) * (BN / 64) * 64) void gemm_bt(
    const ushort* __restrict__ Ag, const ushort* __restrict__ Wt,
    const float* __restrict__ biasg,
    const float* __restrict__ res1f,
    const ushort* __restrict__ resi1, const ushort* __restrict__ resi2,
    OutT* __restrict__ outg,
    int M, int N, int K, int do_gelu, int scatter) {
    constexpr int NWAVE = (BM / 64) * (BN / 64);
    constexpr int NT = NWAVE * 64;
    constexpr int TOT = (BM + BN) * 4;        // 16B chunks per BK tile
    __shared__ ushort Tile[(BM + BN) * BK];   // As then Bs, unpadded (glds layout)
    ushort* As = Tile;
    ushort* Bs = Tile + BM * BK;
    const int tid = threadIdx.x;
    const int wave = tid >> 6, lane = tid & 63;
    const int quad = lane >> 4, l16 = lane & 15;
    const int m0 = blockIdx.y * BM, n0 = blockIdx.x * BN;
    const int wm = (wave / (BN / 64)) * 64, wn = (wave % (BN / 64)) * 64;

    float4v acc[4][4];
    const float4v zero = {0.f, 0.f, 0.f, 0.f};
#pragma unroll
    for (int i = 0; i < 4; i++)
#pragma unroll
        for (int j = 0; j < 4; j++) acc[i][j] = zero;

    for (int k0 = 0; k0 < K; k0 += BK) {
#pragma unroll
        for (int it = 0; it < TOT / NT; it++) {
            int c = tid + it * NT;
            int row = c >> 2, kc = (c & 3) * 8;
            const ushort* src = (row < BM)
                ? Ag + (size_t)(m0 + row) * K + k0 + kc
                : Wt + (size_t)(n0 + row - BM) * K + k0 + kc;
            async_copy16(&Tile[c * 8], src);
        }
        __syncthreads();
        short8 af[4], bfr[4];
#pragma unroll
        for (int i = 0; i < 4; i++)
            af[i] = *reinterpret_cast<const short8*>(&As[(wm + i * 16 + l16) * BK + quad * 8]);
#pragma unroll
        for (int j = 0; j < 4; j++)
            bfr[j] = *reinterpret_cast<const short8*>(&Bs[(wn + j * 16 + l16) * BK + quad * 8]);
#pragma unroll
        for (int j = 0; j < 4; j++)
#pragma unroll
            for (int i = 0; i < 4; i++)
                acc[i][j] = __builtin_amdgcn_mfma_f32_16x16x32_bf16(as_bf(af[i]), as_bf(bfr[j]), acc[i][j], 0, 0, 0);
        __syncthreads();
    }
    // epilogue: C/D layout col=lane&15, row=quad*4+reg
#pragma unroll
    for (int j = 0; j < 4; j++) {
        int cg = n0 + wn + j * 16 + l16;
        float bv = biasg ? biasg[cg] : 0.f;
#pragma unroll
        for (int i = 0; i < 4; i++) {
#pragma unroll
            for (int r = 0; r < 4; r++) {
                int rg = m0 + wm + i * 16 + quad * 4 + r;
                float v = acc[i][j][r] + bv;
                if (do_gelu) v = 0.5f * v * (1.f + erff(v * 0.70710678118654752f));
                size_t idx = (size_t)rg * N + cg;
                if (res1f) v += res1f[idx];
                if (resi1) v += bf2f(resi1[idx]);
                if (resi2) v += bf2f(resi2[idx]);
                size_t dst;
                if (scatter) {   // [B*S, D] -> [B,H,S,DK]
                    int b = rg >> 10, s = rg & 1023;
                    int h = cg >> 6, dk = cg & 63;
                    dst = (((size_t)b * Hc + h) * Sc_ + s) * DKc + dk;
                } else dst = idx;
                if constexpr (sizeof(OutT) == 4) outg[dst] = v;
                else                             outg[dst] = f2bf(v);
            }
        }
    }
}

// ---- Attention: one block per (b,h, 16 Q rows); V from Vt[b,h,dk,s] ----
__global__ __launch_bounds__(256) void attn_kernel(
    const ushort* __restrict__ Qg, const ushort* __restrict__ Kg,
    const ushort* __restrict__ Vt, const float* __restrict__ relg,
    ushort* __restrict__ ctxg) {
    __shared__ ushort Sl[16][Sc_ + 8];
    __shared__ ushort Qs[16][DKc + 8];
    __shared__ float red[16][16];
    __shared__ float rowmax[16], rowinv[16];

    const int blk = blockIdx.x;
    const int qt = blk & 63;
    const int bh = blk >> 6;
    const int h = bh & (Hc - 1);
    const int b = bh >> 4;
    const int tid = threadIdx.x;
    const int wave = tid >> 6, lane = tid & 63;
    const int quad = lane >> 4, l16 = lane & 15;

    if (tid < 128) {
        int r = tid >> 3, c = (tid & 7) * 8;
        short8 v = *reinterpret_cast<const short8*>(
            Qg + ((size_t)bh * Sc_ + qt * 16 + r) * DKc + c);
        *reinterpret_cast<short8*>(&Qs[r][c]) = v;
    }
    __syncthreads();

    short8 aQ[2];
#pragma unroll
    for (int f = 0; f < 2; f++)
        aQ[f] = *reinterpret_cast<const short8*>(&Qs[l16][f * 32 + quad * 8]);

    // pass A: logits = Q K^T / 8 + relbias -> LDS (bf16)
    for (int i = 0; i < 16; i++) {
        int nt = wave + i * 4;
        int t = nt * 16 + l16;
        float4v acc = {0.f, 0.f, 0.f, 0.f};
#pragma unroll
        for (int f = 0; f < 2; f++) {
            short8 bK = *reinterpret_cast<const short8*>(
                Kg + ((size_t)bh * Sc_ + t) * DKc + f * 32 + quad * 8);
            acc = __builtin_amdgcn_mfma_f32_16x16x32_bf16(as_bf(aQ[f]), as_bf(bK), acc, 0, 0, 0);
        }
#pragma unroll
        for (int r = 0; r < 4; r++) {
            int srow = quad * 4 + r;
            int sg = qt * 16 + srow;
            int rel = min(max(t - sg + 63, 0), 126);
            float bias = relg[rel * Hc + h];
            Sl[srow][t] = f2bf(acc[r] * 0.125f + bias);
        }
    }
    __syncthreads();

    // softmax over full row (S=1024) in LDS
    {
        int row = tid >> 4, j = tid & 15;
        float mx = -1e30f;
        for (int i = 0; i < 64; i++) mx = fmaxf(mx, bf2f(Sl[row][j + 16 * i]));
        red[row][j] = mx;
        __syncthreads();
        if (tid < 16) {
            float m = -1e30f;
            for (int k = 0; k < 16; k++) m = fmaxf(m, red[tid][k]);
            rowmax[tid] = m;
        }
        __syncthreads();
        float rm = rowmax[row];
        float sum = 0.f;
        for (int i = 0; i < 64; i++) {
            int c = j + 16 * i;
            float e = __expf(bf2f(Sl[row][c]) - rm);
            sum += e;
            Sl[row][c] = f2bf(e);
        }
        red[row][j] = sum;
        __syncthreads();
        if (tid < 16) {
            float sm = 0.f;
            for (int k = 0; k < 16; k++) sm += red[tid][k];
            rowinv[tid] = 1.f / sm;
        }
        __syncthreads();
    }

    // pass B: ctx = P @ V from Vt rows (coalesced, no LDS staging, no barriers)
    float4v accO = {0.f, 0.f, 0.f, 0.f};
    const int d = wave * 16 + l16;
    const ushort* vrow = Vt + ((size_t)bh * DKc + d) * Sc_;
#pragma unroll 4
    for (int t0 = 0; t0 < Sc_; t0 += 32) {
        short8 aP = *reinterpret_cast<const short8*>(&Sl[l16][t0 + quad * 8]);
        short8 bV = *reinterpret_cast<const short8*>(vrow + t0 + quad * 8);
        accO = __builtin_amdgcn_mfma_f32_16x16x32_bf16(as_bf(aP), as_bf(bV), accO, 0, 0, 0);
    }
#pragma unroll
    for (int r = 0; r < 4; r++) {
        int srow = quad * 4 + r;
        float v = accO[r] * rowinv[srow];
        int s = qt * 16 + srow;
        ctxg[((size_t)b * Sc_ + s) * Dc + h * DKc + d] = f2bf(v);
    }
}

extern "C" void kernel_launch(void* const* d_in, const int* in_sizes, int n_in,
                              void* d_out, int out_size, void* d_ws, size_t ws_size,
                              hipStream_t stream) {
    float* out = (float*)d_out;

    static const int exp_sizes[22] = {
        4194304, 1048576, 1024, 1048576, 1024, 1048576, 1024, 1048576, 1024,
        2032, 1024, 1024, 1024, 1024, 4194304, 4096, 4194304, 1024,
        1048576, 1024, 1024, 1024};
    bool ok = (n_in == 22);
    if (ok) for (int i = 0; i < 22; i++) if (in_sizes[i] != exp_sizes[i]) { ok = false; break; }
    if (!ok) {
        sentinel_kernel<<<(out_size + 255) / 256, 256, 0, stream>>>(out, out_size);
        return;
    }

    const float* x   = (const float*)d_in[0];
    const float* wq  = (const float*)d_in[1];  const float* bq  = (const float*)d_in[2];
    const float* wk  = (const float*)d_in[3];  const float* bk  = (const float*)d_in[4];
    const float* wv  = (const float*)d_in[5];  const float* bv  = (const float*)d_in[6];
    const float* wo  = (const float*)d_in[7];  const float* bo  = (const float*)d_in[8];
    const float* rel = (const float*)d_in[9];
    const float* g1  = (const float*)d_in[10]; const float* be1 = (const float*)d_in[11];
    const float* g2  = (const float*)d_in[12]; const float* be2 = (const float*)d_in[13];
    const float* w1  = (const float*)d_in[14]; const float* b1  = (const float*)d_in[15];
    const float* w2  = (const float*)d_in[16]; const float* b2  = (const float*)d_in[17];
    const float* w3  = (const float*)d_in[18]; const float* b3  = (const float*)d_in[19];
    const float* gf  = (const float*)d_in[20]; const float* bfp = (const float*)d_in[21];

    // ws (64 MiB = 8*NE shorts): [Wts NE][nx NE][Qb NE][Kb NE][Vb NE][Vt NE][..2NE]
    constexpr size_t NE = (size_t)ROWS * Dc;   // 4M elements
    ushort* base = (ushort*)d_ws;
    ushort* Wts = base;               // weight scratch (w1/w2 use all of it)
    ushort* nx  = base + NE;
    ushort* Qb  = base + 2 * NE;
    ushort* Kb  = base + 3 * NE;
    ushort* Vb  = base + 4 * NE;
    ushort* Vt  = base + 5 * NE;
    ushort* ctx = nx;                 // reuse nx (dead after QKV gemms)
    ushort* x1  = Qb;                 // reuse Qb (dead after attn)
    ushort* nx2 = Kb;                 // reuse Kb (dead after attn)
    ushort* hb  = base + 4 * NE;      // [4NE,8NE): Vb/Vt dead after attn
    ushort* yb  = nx;                 // reuse ctx (dead after wo gemm)
    ushort* ly  = Kb;                 // reuse nx2 (dead after w2 gemm)

    dim3 blk256(256), blk128(128);
    dim3 gD64(Dc / 128, ROWS / 64);    // (8, 64): <64,128> tiles
    dim3 gFF(DFFc / 128, ROWS / 128);  // (32, 32): <128,128> tiles
    dim3 cD(Dc / 64, Dc / 64);
    dim3 c1(DFFc / 64, Dc / 64);
    dim3 c2(Dc / 64, DFFc / 64);
    dim3 cV(Sc_ / 64, Bc * Hc);

    ln_kernel<true><<<ROWS, blk256, 0, stream>>>(x, g1, be1, nx);
    wconv_kernel<<<cD, blk256, 0, stream>>>(wq, Wts, Dc, Dc);
    gemm_bt<64, 128, ushort><<<gD64, blk128, 0, stream>>>(nx, Wts, bq, nullptr, nullptr, nullptr, Qb, ROWS, Dc, Dc, 0, 1);
    wconv_kernel<<<cD, blk256, 0, stream>>>(wk, Wts, Dc, Dc);
    gemm_bt<64, 128, ushort><<<gD64, blk128, 0, stream>>>(nx, Wts, bk, nullptr, nullptr, nullptr, Kb, ROWS, Dc, Dc, 0, 1);
    wconv_kernel<<<cD, blk256, 0, stream>>>(wv, Wts, Dc, Dc);
    gemm_bt<64, 128, ushort><<<gD64, blk128, 0, stream>>>(nx, Wts, bv, nullptr, nullptr, nullptr, Vb, ROWS, Dc, Dc, 0, 1);
    vconv_kernel<<<cV, blk256, 0, stream>>>(Vb, Vt);
    attn_kernel<<<ROWS, blk256, 0, stream>>>(Qb, Kb, Vt, rel, ctx);
    wconv_kernel<<<cD, blk256, 0, stream>>>(wo, Wts, Dc, Dc);
    gemm_bt<64, 128, ushort><<<gD64, blk128, 0, stream>>>(ctx, Wts, bo, x, nullptr, nullptr, x1, ROWS, Dc, Dc, 0, 0);
    ln_kernel<false><<<ROWS, blk256, 0, stream>>>(x1, g2, be2, nx2);
    wconv_kernel<<<c1, blk256, 0, stream>>>(w1, Wts, Dc, DFFc);
    gemm_bt<128, 128, ushort><<<gFF, blk256, 0, stream>>>(nx2, Wts, b1, nullptr, nullptr, nullptr, hb, ROWS, DFFc, Dc, 1, 0);
    wconv_kernel<<<c2, blk256, 0, stream>>>(w2, Wts, DFFc, Dc);
    gemm_bt<64, 128, ushort><<<gD64, blk128, 0, stream>>>(hb, Wts, b2, nullptr, nx2, nullptr, yb, ROWS, Dc, DFFc, 0, 0);
    ln_kernel<false><<<ROWS, blk256, 0, stream>>>(yb, gf, bfp, ly);
    wconv_kernel<<<cD, blk256, 0, stream>>>(w3, Wts, Dc, Dc);
    gemm_bt<64, 128, float><<<gD64, blk128, 0, stream>>>(ly, Wts, b3, nullptr, x1, yb, out, ROWS, Dc, Dc, 0, 0);
}

// Round 9
// 542.385 us; speedup vs baseline: 1.8875x; 1.3816x over previous
//
#include <hip/hip_runtime.h>
#include <hip/hip_bf16.h>
#include <math.h>

// TransformerBlock B=4,S=1024,D=1024,H=16,DK=64,DFF=4096. Externals f32, out f32.
// GEMMs: wconv (f32 W -> Wt[N][K] bf16) + double-buffered bt-GEMM (glds 16B, raw
// s_barrier + vmcnt(0), 1 barrier/iter). QKV fused (N=3072). Attention: bf16 scores
// in LDS, vectorized softmax, PV from pre-transposed Vt (no barriers).

constexpr int Bc = 4, Sc_ = 1024, Dc = 1024, Hc = 16, DKc = 64, DFFc = 4096;
constexpr int ROWS = Bc * Sc_;   // 4096
constexpr int BK = 32;

typedef short short8 __attribute__((ext_vector_type(8)));
typedef __bf16 bf16x8 __attribute__((ext_vector_type(8)));
typedef float float4v __attribute__((ext_vector_type(4)));

__device__ __forceinline__ float bf2f(ushort u) {
    union { uint i; float f; } v; v.i = ((uint)u) << 16; return v.f;
}
__device__ __forceinline__ ushort f2bf(float f) {
    union { float f; uint i; } v; v.f = f;
    uint r = v.i + 0x7FFF + ((v.i >> 16) & 1);   // RNE
    return (ushort)(r >> 16);
}
__device__ __forceinline__ bf16x8 as_bf(short8 s) {
    union { short8 s; bf16x8 b; } u; u.s = s; return u.b;
}
__device__ __forceinline__ void async_copy16(void* lds, const void* g) {
    __builtin_amdgcn_global_load_lds((const __attribute__((address_space(1))) uint*)g,
                                     (__attribute__((address_space(3))) uint*)lds, 16, 0, 0);
}
// exact-GELU via Abramowitz-Stegun erf (max abs err 1.5e-7)
__device__ __forceinline__ float gelu_f(float v) {
    float z = v * 0.70710678118654752f;
    float az = fabsf(z);
    float t = 1.f / (1.f + 0.3275911f * az);
    float p = ((((1.061405429f * t - 1.453152027f) * t) + 1.421413741f) * t
               - 0.284496736f) * t + 0.254829592f;
    float y = 1.f - p * t * __expf(-az * az);
    float er = (z < 0.f) ? -y : y;
    return 0.5f * v * (1.f + er);
}

__global__ void sentinel_kernel(float* __restrict__ out, int n) {
    int i = blockIdx.x * 256 + threadIdx.x;
    if (i < n) out[i] = 100.0f;
}

// combined qkv bias
__global__ void bias3_kernel(const float* __restrict__ a, const float* __restrict__ b,
                             const float* __restrict__ c, float* __restrict__ o) {
    int i = blockIdx.x * 256 + threadIdx.x;
    if (i < 1024) o[i] = a[i];
    else if (i < 2048) o[i] = b[i - 1024];
    else if (i < 3072) o[i] = c[i - 2048];
}

// ---- transpose+convert: W[K][N] f32 -> Wt[N][K] bf16, 64x64 tiles ----
__global__ __launch_bounds__(256) void wconv_kernel(const float* __restrict__ W,
                                                    ushort* __restrict__ Wt,
                                                    int K, int N) {
    __shared__ float T[64][65];
    const int kt = blockIdx.y * 64, nt = blockIdx.x * 64;
    const int tid = threadIdx.x;
#pragma unroll
    for (int it = 0; it < 4; it++) {
        int r = it * 16 + (tid >> 4), c = (tid & 15) * 4;
        float4v v = *reinterpret_cast<const float4v*>(W + (size_t)(kt + r) * N + nt + c);
        T[r][c] = v[0]; T[r][c + 1] = v[1]; T[r][c + 2] = v[2]; T[r][c + 3] = v[3];
    }
    __syncthreads();
    int n = tid >> 2, kc = (tid & 3) * 16;
    short8 a, b;
#pragma unroll
    for (int q = 0; q < 8; q++) {
        a[q] = (short)f2bf(T[kc + q][n]);
        b[q] = (short)f2bf(T[kc + 8 + q][n]);
    }
    ushort* dst = Wt + (size_t)(nt + n) * K + kt + kc;
    *reinterpret_cast<short8*>(dst) = a;
    *reinterpret_cast<short8*>(dst + 8) = b;
}

// ---- V transpose: V[b,h,s,dk] bf16 -> Vt[b,h,dk,s] bf16 ----
__global__ __launch_bounds__(256) void vconv_kernel(const ushort* __restrict__ V,
                                                    ushort* __restrict__ Vt) {
    __shared__ ushort T[64][65];
    const int bh = blockIdx.y;
    const int s0 = blockIdx.x * 64;
    const int tid = threadIdx.x;
    const int r = tid >> 2, c = (tid & 3) * 16;
    const ushort* src = V + ((size_t)bh * Sc_ + s0 + r) * DKc + c;
    short8 a = *reinterpret_cast<const short8*>(src);
    short8 b = *reinterpret_cast<const short8*>(src + 8);
#pragma unroll
    for (int q = 0; q < 8; q++) { T[r][c + q] = (ushort)a[q]; T[r][c + 8 + q] = (ushort)b[q]; }
    __syncthreads();
    const int dk = tid >> 2, sc2 = (tid & 3) * 16;
    short8 o0, o1;
#pragma unroll
    for (int q = 0; q < 8; q++) { o0[q] = (short)T[sc2 + q][dk]; o1[q] = (short)T[sc2 + 8 + q][dk]; }
    ushort* dst = Vt + ((size_t)bh * DKc + dk) * Sc_ + s0 + sc2;
    *reinterpret_cast<short8*>(dst) = o0;
    *reinterpret_cast<short8*>(dst + 8) = o1;
}

// ---- LayerNorm: one block per row of D=1024 ----
template<bool IN_F32>
__global__ __launch_bounds__(256) void ln_kernel(const void* __restrict__ xin,
                                                 const float* __restrict__ g,
                                                 const float* __restrict__ be,
                                                 ushort* __restrict__ out) {
    int row = blockIdx.x;
    int tid = threadIdx.x;
    float v0[4], s = 0.f, ss = 0.f;
#pragma unroll
    for (int i = 0; i < 4; i++) {
        int c = tid + i * 256;
        float f = IN_F32 ? ((const float*)xin)[(size_t)row * Dc + c]
                         : bf2f(((const ushort*)xin)[(size_t)row * Dc + c]);
        v0[i] = f; s += f; ss += f * f;
    }
#pragma unroll
    for (int off = 32; off > 0; off >>= 1) {
        s += __shfl_down(s, off);
        ss += __shfl_down(ss, off);
    }
    __shared__ float red[8];
    __shared__ float stat[2];
    int wave = tid >> 6, lane = tid & 63;
    if (lane == 0) { red[wave] = s; red[wave + 4] = ss; }
    __syncthreads();
    if (tid == 0) {
        float a = 0.f, b = 0.f;
        for (int w = 0; w < 4; w++) { a += red[w]; b += red[w + 4]; }
        stat[0] = a; stat[1] = b;
    }
    __syncthreads();
    float mean = stat[0] * (1.f / Dc);
    float var  = stat[1] * (1.f / Dc) - mean * mean;
    float inv  = rsqrtf(var + 1e-5f);
#pragma unroll
    for (int i = 0; i < 4; i++) {
        int c = tid + i * 256;
        float nv = (v0[i] - mean) * inv * g[c] + be[c];
        out[(size_t)row * Dc + c] = f2bf(nv);
    }
}

// ---- bt-GEMM, double-buffered: C = A[M][K] @ Wt[N][K]^T + bias, fused epilogue ----
// mode: 0 = plain [M][N] out; 1 = fused-QKV scatter (N=3072 -> Q|K|V [B,H,S,DK])
template<int BM, int BN, typename OutT>
__global__ __launch_bounds__(256) void gemm_bt(
    const ushort* __restrict__ Ag, const ushort* __restrict__ Wt,
    const float* __restrict__ biasg,
    const float* __restrict__ res1f,
    const ushort* __restrict__ resi1, const ushort* __restrict__ resi2,
    OutT* __restrict__ outg,
    int M, int N, int K, int do_gelu, int mode) {
    constexpr int WN = BN / 64;            // waves along n
    constexpr int WM = 4 / WN;             // waves along m
    constexpr int MI = BM / (WM * 16);     // m-frags per wave (4 at BM=128, 2 at BM=64)
    constexpr int TSZ = (BM + BN) * BK;    // shorts per LDS buffer
    constexpr int TOT = (BM + BN) * 4;     // 16B chunks per buffer
    __shared__ ushort Tile[2 * TSZ];
    const int tid = threadIdx.x;
    const int wave = tid >> 6, lane = tid & 63;
    const int quad = lane >> 4, l16 = lane & 15;
    const int m0 = blockIdx.y * BM, n0 = blockIdx.x * BN;
    const int wm = (wave / WN) * (MI * 16), wn = (wave % WN) * 64;

    float4v acc[MI][4];
    const float4v zero = {0.f, 0.f, 0.f, 0.f};
#pragma unroll
    for (int i = 0; i < MI; i++)
#pragma unroll
        for (int j = 0; j < 4; j++) acc[i][j] = zero;

    auto stage = [&](int buf, int k0) {
#pragma unroll
        for (int it = 0; it < TOT / 256; it++) {
            int c = tid + it * 256;
            int row = c >> 2, kc = (c & 3) * 8;
            const ushort* src = (row < BM)
                ? Ag + (size_t)(m0 + row) * K + k0 + kc
                : Wt + (size_t)(n0 + row - BM) * K + k0 + kc;
            async_copy16(&Tile[buf * TSZ + c * 8], src);
        }
    };

    const int nit = K / BK;
    stage(0, 0);
    for (int i = 0; i < nit; i++) {
        int buf = i & 1;
        __builtin_amdgcn_sched_barrier(0);
        __builtin_amdgcn_s_waitcnt(0x0F70);   // vmcnt(0): my glds for buf done
        __builtin_amdgcn_s_barrier();         // all waves agree
        __builtin_amdgcn_sched_barrier(0);
        if (i + 1 < nit) stage(buf ^ 1, (i + 1) * BK);   // prefetch overlaps compute
        __builtin_amdgcn_sched_barrier(0);
        const ushort* Asb = &Tile[buf * TSZ];
        const ushort* Bsb = &Tile[buf * TSZ + BM * BK];
        short8 af[MI], bfr[4];
#pragma unroll
        for (int ii = 0; ii < MI; ii++)
            af[ii] = *reinterpret_cast<const short8*>(&Asb[(wm + ii * 16 + l16) * BK + quad * 8]);
#pragma unroll
        for (int j = 0; j < 4; j++)
            bfr[j] = *reinterpret_cast<const short8*>(&Bsb[(wn + j * 16 + l16) * BK + quad * 8]);
#pragma unroll
        for (int j = 0; j < 4; j++)
#pragma unroll
            for (int ii = 0; ii < MI; ii++)
                acc[ii][j] = __builtin_amdgcn_mfma_f32_16x16x32_bf16(as_bf(af[ii]), as_bf(bfr[j]), acc[ii][j], 0, 0, 0);
        // no trailing barrier needed: next iter's top barrier orders buf reuse
    }
    __builtin_amdgcn_s_barrier();   // all reads done before epilogue (paranoia, cheap)

    // epilogue: C/D layout col=lane&15, row=quad*4+reg
#pragma unroll
    for (int j = 0; j < 4; j++) {
        int cg = n0 + wn + j * 16 + l16;
        float bv = biasg ? biasg[cg] : 0.f;
#pragma unroll
        for (int i = 0; i < MI; i++) {
#pragma unroll
            for (int r = 0; r < 4; r++) {
                int rg = m0 + wm + i * 16 + quad * 4 + r;
                float v = acc[i][j][r] + bv;
                if (do_gelu) v = gelu_f(v);
                size_t idx = (size_t)rg * N + cg;
                if (res1f) v += res1f[idx];
                if (resi1) v += bf2f(resi1[idx]);
                if (resi2) v += bf2f(resi2[idx]);
                size_t dst;
                if (mode == 1) {   // fused QKV: cg in [0,3072)
                    int which = cg >> 10, wr2 = cg & 1023;
                    int h = wr2 >> 6, dk = wr2 & 63;
                    int b = rg >> 10, s = rg & 1023;
                    dst = (size_t)which * ((size_t)ROWS * Dc)
                        + (((size_t)b * Hc + h) * Sc_ + s) * DKc + dk;
                } else dst = idx;
                if constexpr (sizeof(OutT) == 4) outg[dst] = v;
                else                             outg[dst] = f2bf(v);
            }
        }
    }
}

// ---- Attention: one block per (b,h, 16 Q rows); V from Vt[b,h,dk,s] ----
__global__ __launch_bounds__(256) void attn_kernel(
    const ushort* __restrict__ Qg, const ushort* __restrict__ Kg,
    const ushort* __restrict__ Vt, const float* __restrict__ relg,
    ushort* __restrict__ ctxg) {
    __shared__ ushort Sl[16][Sc_ + 8];
    __shared__ ushort Qs[16][DKc + 8];
    __shared__ float red[16][16];
    __shared__ float rowmax[16], rowinv[16];

    const int blk = blockIdx.x;
    const int qt = blk & 63;
    const int bh = blk >> 6;
    const int h = bh & (Hc - 1);
    const int b = bh >> 4;
    const int tid = threadIdx.x;
    const int wave = tid >> 6, lane = tid & 63;
    const int quad = lane >> 4, l16 = lane & 15;

    if (tid < 128) {
        int r = tid >> 3, c = (tid & 7) * 8;
        short8 v = *reinterpret_cast<const short8*>(
            Qg + ((size_t)bh * Sc_ + qt * 16 + r) * DKc + c);
        *reinterpret_cast<short8*>(&Qs[r][c]) = v;
    }
    __syncthreads();

    short8 aQ[2];
#pragma unroll
    for (int f = 0; f < 2; f++)
        aQ[f] = *reinterpret_cast<const short8*>(&Qs[l16][f * 32 + quad * 8]);

    // pass A: logits = Q K^T / 8 + relbias -> LDS (bf16)
    for (int i = 0; i < 16; i++) {
        int nt = wave + i * 4;
        int t = nt * 16 + l16;
        float4v acc = {0.f, 0.f, 0.f, 0.f};
#pragma unroll
        for (int f = 0; f < 2; f++) {
            short8 bK = *reinterpret_cast<const short8*>(
                Kg + ((size_t)bh * Sc_ + t) * DKc + f * 32 + quad * 8);
            acc = __builtin_amdgcn_mfma_f32_16x16x32_bf16(as_bf(aQ[f]), as_bf(bK), acc, 0, 0, 0);
        }
#pragma unroll
        for (int r = 0; r < 4; r++) {
            int srow = quad * 4 + r;
            int sg = qt * 16 + srow;
            int rel = min(max(t - sg + 63, 0), 126);
            float bias = relg[rel * Hc + h];
            Sl[srow][t] = f2bf(acc[r] * 0.125f + bias);
        }
    }
    __syncthreads();

    // softmax: vectorized b128 passes; thread = (row, chunk), cols chunk*8 + i*128
    {
        int row = tid >> 4, chunk = tid & 15;
        float mx = -1e30f;
#pragma unroll
        for (int i = 0; i < 8; i++) {
            short8 s8 = *reinterpret_cast<const short8*>(&Sl[row][chunk * 8 + i * 128]);
#pragma unroll
            for (int q = 0; q < 8; q++) mx = fmaxf(mx, bf2f((ushort)s8[q]));
        }
        red[row][chunk] = mx;
        __syncthreads();
        if (tid < 16) {
            float m = -1e30f;
            for (int k = 0; k < 16; k++) m = fmaxf(m, red[tid][k]);
            rowmax[tid] = m;
        }
        __syncthreads();
        float rm = rowmax[row];
        float sum = 0.f;
#pragma unroll
        for (int i = 0; i < 8; i++) {
            short8 s8 = *reinterpret_cast<const short8*>(&Sl[row][chunk * 8 + i * 128]);
            short8 o8;
#pragma unroll
            for (int q = 0; q < 8; q++) {
                float e = __expf(bf2f((ushort)s8[q]) - rm);
                sum += e;
                o8[q] = (short)f2bf(e);
            }
            *reinterpret_cast<short8*>(&Sl[row][chunk * 8 + i * 128]) = o8;
        }
        red[row][chunk] = sum;
        __syncthreads();
        if (tid < 16) {
            float sm = 0.f;
            for (int k = 0; k < 16; k++) sm += red[tid][k];
            rowinv[tid] = 1.f / sm;
        }
        __syncthreads();
    }

    // pass B: ctx = P @ V from Vt rows (no LDS staging, no barriers)
    float4v accO = {0.f, 0.f, 0.f, 0.f};
    const int d = wave * 16 + l16;
    const ushort* vrow = Vt + ((size_t)bh * DKc + d) * Sc_;
#pragma unroll 4
    for (int t0 = 0; t0 < Sc_; t0 += 32) {
        short8 aP = *reinterpret_cast<const short8*>(&Sl[l16][t0 + quad * 8]);
        short8 bV = *reinterpret_cast<const short8*>(vrow + t0 + quad * 8);
        accO = __builtin_amdgcn_mfma_f32_16x16x32_bf16(as_bf(aP), as_bf(bV), accO, 0, 0, 0);
    }
#pragma unroll
    for (int r = 0; r < 4; r++) {
        int srow = quad * 4 + r;
        float v = accO[r] * rowinv[srow];
        int s = qt * 16 + srow;
        ctxg[((size_t)b * Sc_ + s) * Dc + h * DKc + d] = f2bf(v);
    }
}

extern "C" void kernel_launch(void* const* d_in, const int* in_sizes, int n_in,
                              void* d_out, int out_size, void* d_ws, size_t ws_size,
                              hipStream_t stream) {
    float* out = (float*)d_out;

    static const int exp_sizes[22] = {
        4194304, 1048576, 1024, 1048576, 1024, 1048576, 1024, 1048576, 1024,
        2032, 1024, 1024, 1024, 1024, 4194304, 4096, 4194304, 1024,
        1048576, 1024, 1024, 1024};
    bool ok = (n_in == 22);
    if (ok) for (int i = 0; i < 22; i++) if (in_sizes[i] != exp_sizes[i]) { ok = false; break; }
    if (!ok) {
        sentinel_kernel<<<(out_size + 255) / 256, 256, 0, stream>>>(out, out_size);
        return;
    }

    const float* x   = (const float*)d_in[0];
    const float* wq  = (const float*)d_in[1];  const float* bq  = (const float*)d_in[2];
    const float* wk  = (const float*)d_in[3];  const float* bk  = (const float*)d_in[4];
    const float* wv  = (const float*)d_in[5];  const float* bv  = (const float*)d_in[6];
    const float* wo  = (const float*)d_in[7];  const float* bo  = (const float*)d_in[8];
    const float* rel = (const float*)d_in[9];
    const float* g1  = (const float*)d_in[10]; const float* be1 = (const float*)d_in[11];
    const float* g2  = (const float*)d_in[12]; const float* be2 = (const float*)d_in[13];
    const float* w1  = (const float*)d_in[14]; const float* b1  = (const float*)d_in[15];
    const float* w2  = (const float*)d_in[16]; const float* b2  = (const float*)d_in[17];
    const float* w3  = (const float*)d_in[18]; const float* b3  = (const float*)d_in[19];
    const float* gf  = (const float*)d_in[20]; const float* bfp = (const float*)d_in[21];

    // ws (64 MiB = 8*NE shorts): [0]=Wts [1]=nx/ctx/yb [2]=Qb/x1 [3]=Kb/nx2/ly
    // [4]=Vb [5]=Vt [4..7]=hb (FF phase); bqkv floats at [6] (QKV phase only)
    constexpr size_t NE = (size_t)ROWS * Dc;   // 4M elements
    ushort* base = (ushort*)d_ws;
    ushort* Wts  = base;
    ushort* nx   = base + NE;
    ushort* Qb   = base + 2 * NE;              // Kb=Qb+NE, Vb=Qb+2NE contiguous
    ushort* Kb   = base + 3 * NE;
    ushort* Vb   = base + 4 * NE;
    ushort* Vt   = base + 5 * NE;
    float*  bqkv = (float*)(base + 6 * NE);
    ushort* ctx  = nx;
    ushort* x1   = Qb;
    ushort* nx2  = Kb;
    ushort* hb   = base + 4 * NE;              // 4NE shorts = 32MB
    ushort* yb   = nx;
    ushort* ly   = Kb;

    dim3 blk(256);
    dim3 gQKV(3072 / 128, ROWS / 64);   // (24, 64)
    dim3 gD(Dc / 128, ROWS / 64);       // (8, 64)
    dim3 gFF(DFFc / 128, ROWS / 128);   // (32, 32)
    dim3 cD(Dc / 64, Dc / 64);
    dim3 c1(DFFc / 64, Dc / 64);
    dim3 c2(Dc / 64, DFFc / 64);
    dim3 cV(Sc_ / 64, Bc * Hc);

    ln_kernel<true><<<ROWS, blk, 0, stream>>>(x, g1, be1, nx);
    wconv_kernel<<<cD, blk, 0, stream>>>(wq, Wts, Dc, Dc);
    wconv_kernel<<<cD, blk, 0, stream>>>(wk, Wts + (size_t)1024 * 1024, Dc, Dc);
    wconv_kernel<<<cD, blk, 0, stream>>>(wv, Wts + (size_t)2048 * 1024, Dc, Dc);
    bias3_kernel<<<12, blk, 0, stream>>>(bq, bk, bv, bqkv);
    gemm_bt<64, 128, ushort><<<gQKV, blk, 0, stream>>>(nx, Wts, bqkv, nullptr, nullptr, nullptr, Qb, ROWS, 3072, Dc, 0, 1);
    vconv_kernel<<<cV, blk, 0, stream>>>(Vb, Vt);
    attn_kernel<<<ROWS, blk, 0, stream>>>(Qb, Kb, Vt, rel, ctx);
    wconv_kernel<<<cD, blk, 0, stream>>>(wo, Wts, Dc, Dc);
    gemm_bt<64, 128, ushort><<<gD, blk, 0, stream>>>(ctx, Wts, bo, x, nullptr, nullptr, x1, ROWS, Dc, Dc, 0, 0);
    ln_kernel<false><<<ROWS, blk, 0, stream>>>(x1, g2, be2, nx2);
    wconv_kernel<<<c1, blk, 0, stream>>>(w1, Wts, Dc, DFFc);
    gemm_bt<128, 128, ushort><<<gFF, blk, 0, stream>>>(nx2, Wts, b1, nullptr, nullptr, nullptr, hb, ROWS, DFFc, Dc, 1, 0);
    wconv_kernel<<<c2, blk, 0, stream>>>(w2, Wts, DFFc, Dc);
    gemm_bt<64, 128, ushort><<<gD, blk, 0, stream>>>(hb, Wts, b2, nullptr, nx2, nullptr, yb, ROWS, Dc, DFFc, 0, 0);
    ln_kernel<false><<<ROWS, blk, 0, stream>>>(yb, gf, bfp, ly);
    wconv_kernel<<<cD, blk, 0, stream>>>(w3, Wts, Dc, Dc);
    gemm_bt<64, 128, float><<<gD, blk, 0, stream>>>(ly, Wts, b3, nullptr, x1, yb, out, ROWS, Dc, Dc, 0, 0);
}

// Round 10
// 523.223 us; speedup vs baseline: 1.9567x; 1.0366x over previous
//
#include <hip/hip_runtime.h>
#include <hip/hip_bf16.h>
#include <math.h>

// TransformerBlock B=4,S=1024,D=1024,H=16,DK=64,DFF=4096. Externals f32, out f32.
// GEMMs: wconv (f32 W -> Wt[N][K] bf16) + double-buffered bt-GEMM (glds 16B, raw
// s_barrier + vmcnt(0), 1 barrier/iter). QKV fused (N=3072). Attention: rel-bias in
// LDS, Q frags direct from global, wave-local shuffle softmax (3 barriers total),
// PV from pre-transposed Vt (no barriers).

constexpr int Bc = 4, Sc_ = 1024, Dc = 1024, Hc = 16, DKc = 64, DFFc = 4096;
constexpr int ROWS = Bc * Sc_;   // 4096
constexpr int BK = 32;

typedef short short8 __attribute__((ext_vector_type(8)));
typedef __bf16 bf16x8 __attribute__((ext_vector_type(8)));
typedef float float4v __attribute__((ext_vector_type(4)));

__device__ __forceinline__ float bf2f(ushort u) {
    union { uint i; float f; } v; v.i = ((uint)u) << 16; return v.f;
}
__device__ __forceinline__ ushort f2bf(float f) {
    union { float f; uint i; } v; v.f = f;
    uint r = v.i + 0x7FFF + ((v.i >> 16) & 1);   // RNE
    return (ushort)(r >> 16);
}
__device__ __forceinline__ bf16x8 as_bf(short8 s) {
    union { short8 s; bf16x8 b; } u; u.s = s; return u.b;
}
__device__ __forceinline__ void async_copy16(void* lds, const void* g) {
    __builtin_amdgcn_global_load_lds((const __attribute__((address_space(1))) uint*)g,
                                     (__attribute__((address_space(3))) uint*)lds, 16, 0, 0);
}
// exact-GELU via Abramowitz-Stegun erf (max abs err 1.5e-7)
__device__ __forceinline__ float gelu_f(float v) {
    float z = v * 0.70710678118654752f;
    float az = fabsf(z);
    float t = 1.f / (1.f + 0.3275911f * az);
    float p = ((((1.061405429f * t - 1.453152027f) * t) + 1.421413741f) * t
               - 0.284496736f) * t + 0.254829592f;
    float y = 1.f - p * t * __expf(-az * az);
    float er = (z < 0.f) ? -y : y;
    return 0.5f * v * (1.f + er);
}

__global__ void sentinel_kernel(float* __restrict__ out, int n) {
    int i = blockIdx.x * 256 + threadIdx.x;
    if (i < n) out[i] = 100.0f;
}

// combined qkv bias
__global__ void bias3_kernel(const float* __restrict__ a, const float* __restrict__ b,
                             const float* __restrict__ c, float* __restrict__ o) {
    int i = blockIdx.x * 256 + threadIdx.x;
    if (i < 1024) o[i] = a[i];
    else if (i < 2048) o[i] = b[i - 1024];
    else if (i < 3072) o[i] = c[i - 2048];
}

// ---- transpose+convert: W[K][N] f32 -> Wt[N][K] bf16, 64x64 tiles ----
__global__ __launch_bounds__(256) void wconv_kernel(const float* __restrict__ W,
                                                    ushort* __restrict__ Wt,
                                                    int K, int N) {
    __shared__ float T[64][65];
    const int kt = blockIdx.y * 64, nt = blockIdx.x * 64;
    const int tid = threadIdx.x;
#pragma unroll
    for (int it = 0; it < 4; it++) {
        int r = it * 16 + (tid >> 4), c = (tid & 15) * 4;
        float4v v = *reinterpret_cast<const float4v*>(W + (size_t)(kt + r) * N + nt + c);
        T[r][c] = v[0]; T[r][c + 1] = v[1]; T[r][c + 2] = v[2]; T[r][c + 3] = v[3];
    }
    __syncthreads();
    int n = tid >> 2, kc = (tid & 3) * 16;
    short8 a, b;
#pragma unroll
    for (int q = 0; q < 8; q++) {
        a[q] = (short)f2bf(T[kc + q][n]);
        b[q] = (short)f2bf(T[kc + 8 + q][n]);
    }
    ushort* dst = Wt + (size_t)(nt + n) * K + kt + kc;
    *reinterpret_cast<short8*>(dst) = a;
    *reinterpret_cast<short8*>(dst + 8) = b;
}

// ---- V transpose: V[b,h,s,dk] bf16 -> Vt[b,h,dk,s] bf16 ----
__global__ __launch_bounds__(256) void vconv_kernel(const ushort* __restrict__ V,
                                                    ushort* __restrict__ Vt) {
    __shared__ ushort T[64][65];
    const int bh = blockIdx.y;
    const int s0 = blockIdx.x * 64;
    const int tid = threadIdx.x;
    const int r = tid >> 2, c = (tid & 3) * 16;
    const ushort* src = V + ((size_t)bh * Sc_ + s0 + r) * DKc + c;
    short8 a = *reinterpret_cast<const short8*>(src);
    short8 b = *reinterpret_cast<const short8*>(src + 8);
#pragma unroll
    for (int q = 0; q < 8; q++) { T[r][c + q] = (ushort)a[q]; T[r][c + 8 + q] = (ushort)b[q]; }
    __syncthreads();
    const int dk = tid >> 2, sc2 = (tid & 3) * 16;
    short8 o0, o1;
#pragma unroll
    for (int q = 0; q < 8; q++) { o0[q] = (short)T[sc2 + q][dk]; o1[q] = (short)T[sc2 + 8 + q][dk]; }
    ushort* dst = Vt + ((size_t)bh * DKc + dk) * Sc_ + s0 + sc2;
    *reinterpret_cast<short8*>(dst) = o0;
    *reinterpret_cast<short8*>(dst + 8) = o1;
}

// ---- LayerNorm: one block per row of D=1024 ----
template<bool IN_F32>
__global__ __launch_bounds__(256) void ln_kernel(const void* __restrict__ xin,
                                                 const float* __restrict__ g,
                                                 const float* __restrict__ be,
                                                 ushort* __restrict__ out) {
    int row = blockIdx.x;
    int tid = threadIdx.x;
    float v0[4], s = 0.f, ss = 0.f;
#pragma unroll
    for (int i = 0; i < 4; i++) {
        int c = tid + i * 256;
        float f = IN_F32 ? ((const float*)xin)[(size_t)row * Dc + c]
                         : bf2f(((const ushort*)xin)[(size_t)row * Dc + c]);
        v0[i] = f; s += f; ss += f * f;
    }
#pragma unroll
    for (int off = 32; off > 0; off >>= 1) {
        s += __shfl_down(s, off);
        ss += __shfl_down(ss, off);
    }
    __shared__ float red[8];
    __shared__ float stat[2];
    int wave = tid >> 6, lane = tid & 63;
    if (lane == 0) { red[wave] = s; red[wave + 4] = ss; }
    __syncthreads();
    if (tid == 0) {
        float a = 0.f, b = 0.f;
        for (int w = 0; w < 4; w++) { a += red[w]; b += red[w + 4]; }
        stat[0] = a; stat[1] = b;
    }
    __syncthreads();
    float mean = stat[0] * (1.f / Dc);
    float var  = stat[1] * (1.f / Dc) - mean * mean;
    float inv  = rsqrtf(var + 1e-5f);
#pragma unroll
    for (int i = 0; i < 4; i++) {
        int c = tid + i * 256;
        float nv = (v0[i] - mean) * inv * g[c] + be[c];
        out[(size_t)row * Dc + c] = f2bf(nv);
    }
}

// ---- bt-GEMM, double-buffered: C = A[M][K] @ Wt[N][K]^T + bias, fused epilogue ----
// mode: 0 = plain [M][N] out; 1 = fused-QKV scatter (N=3072 -> Q|K|V [B,H,S,DK])
template<int BM, int BN, typename OutT>
__global__ __launch_bounds__(256) void gemm_bt(
    const ushort* __restrict__ Ag, const ushort* __restrict__ Wt,
    const float* __restrict__ biasg,
    const float* __restrict__ res1f,
    const ushort* __restrict__ resi1, const ushort* __restrict__ resi2,
    OutT* __restrict__ outg,
    int M, int N, int K, int do_gelu, int mode) {
    constexpr int WN = BN / 64;            // waves along n
    constexpr int WM = 4 / WN;             // waves along m
    constexpr int MI = BM / (WM * 16);     // m-frags per wave
    constexpr int TSZ = (BM + BN) * BK;    // shorts per LDS buffer
    constexpr int TOT = (BM + BN) * 4;     // 16B chunks per buffer
    __shared__ ushort Tile[2 * TSZ];
    const int tid = threadIdx.x;
    const int wave = tid >> 6, lane = tid & 63;
    const int quad = lane >> 4, l16 = lane & 15;
    const int m0 = blockIdx.y * BM, n0 = blockIdx.x * BN;
    const int wm = (wave / WN) * (MI * 16), wn = (wave % WN) * 64;

    float4v acc[MI][4];
    const float4v zero = {0.f, 0.f, 0.f, 0.f};
#pragma unroll
    for (int i = 0; i < MI; i++)
#pragma unroll
        for (int j = 0; j < 4; j++) acc[i][j] = zero;

    auto stage = [&](int buf, int k0) {
#pragma unroll
        for (int it = 0; it < TOT / 256; it++) {
            int c = tid + it * 256;
            int row = c >> 2, kc = (c & 3) * 8;
            const ushort* src = (row < BM)
                ? Ag + (size_t)(m0 + row) * K + k0 + kc
                : Wt + (size_t)(n0 + row - BM) * K + k0 + kc;
            async_copy16(&Tile[buf * TSZ + c * 8], src);
        }
    };

    const int nit = K / BK;
    stage(0, 0);
    for (int i = 0; i < nit; i++) {
        int buf = i & 1;
        __builtin_amdgcn_sched_barrier(0);
        __builtin_amdgcn_s_waitcnt(0x0F70);   // vmcnt(0): my glds for buf done
        __builtin_amdgcn_s_barrier();         // all waves agree
        __builtin_amdgcn_sched_barrier(0);
        if (i + 1 < nit) stage(buf ^ 1, (i + 1) * BK);   // prefetch overlaps compute
        __builtin_amdgcn_sched_barrier(0);
        const ushort* Asb = &Tile[buf * TSZ];
        const ushort* Bsb = &Tile[buf * TSZ + BM * BK];
        short8 af[MI], bfr[4];
#pragma unroll
        for (int ii = 0; ii < MI; ii++)
            af[ii] = *reinterpret_cast<const short8*>(&Asb[(wm + ii * 16 + l16) * BK + quad * 8]);
#pragma unroll
        for (int j = 0; j < 4; j++)
            bfr[j] = *reinterpret_cast<const short8*>(&Bsb[(wn + j * 16 + l16) * BK + quad * 8]);
#pragma unroll
        for (int j = 0; j < 4; j++)
#pragma unroll
            for (int ii = 0; ii < MI; ii++)
                acc[ii][j] = __builtin_amdgcn_mfma_f32_16x16x32_bf16(as_bf(af[ii]), as_bf(bfr[j]), acc[ii][j], 0, 0, 0);
    }
    __builtin_amdgcn_s_barrier();

    // epilogue: C/D layout col=lane&15, row=quad*4+reg
#pragma unroll
    for (int j = 0; j < 4; j++) {
        int cg = n0 + wn + j * 16 + l16;
        float bv = biasg ? biasg[cg] : 0.f;
#pragma unroll
        for (int i = 0; i < MI; i++) {
#pragma unroll
            for (int r = 0; r < 4; r++) {
                int rg = m0 + wm + i * 16 + quad * 4 + r;
                float v = acc[i][j][r] + bv;
                if (do_gelu) v = gelu_f(v);
                size_t idx = (size_t)rg * N + cg;
                if (res1f) v += res1f[idx];
                if (resi1) v += bf2f(resi1[idx]);
                if (resi2) v += bf2f(resi2[idx]);
                size_t dst;
                if (mode == 1) {   // fused QKV: cg in [0,3072)
                    int which = cg >> 10, wr2 = cg & 1023;
                    int h = wr2 >> 6, dk = wr2 & 63;
                    int b = rg >> 10, s = rg & 1023;
                    dst = (size_t)which * ((size_t)ROWS * Dc)
                        + (((size_t)b * Hc + h) * Sc_ + s) * DKc + dk;
                } else dst = idx;
                if constexpr (sizeof(OutT) == 4) outg[dst] = v;
                else                             outg[dst] = f2bf(v);
            }
        }
    }
}

// ---- Attention: one block per (b,h, 16 Q rows); V from Vt[b,h,dk,s] ----
__global__ __launch_bounds__(256) void attn_kernel(
    const ushort* __restrict__ Qg, const ushort* __restrict__ Kg,
    const ushort* __restrict__ Vt, const float* __restrict__ relg,
    ushort* __restrict__ ctxg) {
    __shared__ ushort Sl[16][Sc_ + 8];
    __shared__ float bias_s[128];
    __shared__ float rowinv[16];

    const int blk = blockIdx.x;
    const int qt = blk & 63;
    const int bh = blk >> 6;
    const int h = bh & (Hc - 1);
    const int b = bh >> 4;
    const int tid = threadIdx.x;
    const int wave = tid >> 6, lane = tid & 63;
    const int quad = lane >> 4, l16 = lane & 15;

    if (tid < 127) bias_s[tid] = relg[tid * Hc + h];

    // Q fragments direct from global, pre-scaled by 1/8 (exact pow2)
    short8 aQ[2];
    const ushort* qrow = Qg + ((size_t)bh * Sc_ + qt * 16 + l16) * DKc;
#pragma unroll
    for (int f = 0; f < 2; f++) {
        short8 v = *reinterpret_cast<const short8*>(qrow + f * 32 + quad * 8);
#pragma unroll
        for (int q = 0; q < 8; q++) v[q] = (short)f2bf(bf2f((ushort)v[q]) * 0.125f);
        aQ[f] = v;
    }
    __syncthreads();   // bias_s ready

    // pass A: logits = (Q/8) K^T + relbias -> LDS (bf16)
    const int sg0 = qt * 16 + quad * 4;
    for (int i = 0; i < 16; i++) {
        int t = (wave + i * 4) * 16 + l16;
        float4v acc = {0.f, 0.f, 0.f, 0.f};
#pragma unroll
        for (int f = 0; f < 2; f++) {
            short8 bK = *reinterpret_cast<const short8*>(
                Kg + ((size_t)bh * Sc_ + t) * DKc + f * 32 + quad * 8);
            acc = __builtin_amdgcn_mfma_f32_16x16x32_bf16(as_bf(aQ[f]), as_bf(bK), acc, 0, 0, 0);
        }
#pragma unroll
        for (int r = 0; r < 4; r++) {
            int rel = min(max(t - (sg0 + r) + 63, 0), 126);
            Sl[quad * 4 + r][t] = f2bf(acc[r] + bias_s[rel]);
        }
    }
    __syncthreads();

    // softmax: row = wave*4+quad, 16 lanes per row, single LDS read into regs
    {
        const int row = wave * 4 + quad;
        short8 buf[8];
        float mx = -1e30f;
#pragma unroll
        for (int i = 0; i < 8; i++) {
            buf[i] = *reinterpret_cast<const short8*>(&Sl[row][l16 * 8 + i * 128]);
#pragma unroll
            for (int q = 0; q < 8; q++) mx = fmaxf(mx, bf2f((ushort)buf[i][q]));
        }
#pragma unroll
        for (int m = 1; m < 16; m <<= 1) mx = fmaxf(mx, __shfl_xor(mx, m));
        float sum = 0.f;
#pragma unroll
        for (int i = 0; i < 8; i++) {
            short8 o8;
#pragma unroll
            for (int q = 0; q < 8; q++) {
                float e = __expf(bf2f((ushort)buf[i][q]) - mx);
                sum += e;
                o8[q] = (short)f2bf(e);
            }
            *reinterpret_cast<short8*>(&Sl[row][l16 * 8 + i * 128]) = o8;
        }
#pragma unroll
        for (int m = 1; m < 16; m <<= 1) sum += __shfl_xor(sum, m);
        if (l16 == 0) rowinv[row] = 1.f / sum;
    }
    __syncthreads();

    // pass B: ctx = P @ V from Vt rows (no LDS staging, no barriers)
    float4v accO = {0.f, 0.f, 0.f, 0.f};
    const int d = wave * 16 + l16;
    const ushort* vrow = Vt + ((size_t)bh * DKc + d) * Sc_;
#pragma unroll 4
    for (int t0 = 0; t0 < Sc_; t0 += 32) {
        short8 aP = *reinterpret_cast<const short8*>(&Sl[l16][t0 + quad * 8]);
        short8 bV = *reinterpret_cast<const short8*>(vrow + t0 + quad * 8);
        accO = __builtin_amdgcn_mfma_f32_16x16x32_bf16(as_bf(aP), as_bf(bV), accO, 0, 0, 0);
    }
#pragma unroll
    for (int r = 0; r < 4; r++) {
        int srow = quad * 4 + r;
        float v = accO[r] * rowinv[srow];
        int s = qt * 16 + srow;
        ctxg[((size_t)b * Sc_ + s) * Dc + h * DKc + d] = f2bf(v);
    }
}

extern "C" void kernel_launch(void* const* d_in, const int* in_sizes, int n_in,
                              void* d_out, int out_size, void* d_ws, size_t ws_size,
                              hipStream_t stream) {
    float* out = (float*)d_out;

    static const int exp_sizes[22] = {
        4194304, 1048576, 1024, 1048576, 1024, 1048576, 1024, 1048576, 1024,
        2032, 1024, 1024, 1024, 1024, 4194304, 4096, 4194304, 1024,
        1048576, 1024, 1024, 1024};
    bool ok = (n_in == 22);
    if (ok) for (int i = 0; i < 22; i++) if (in_sizes[i] != exp_sizes[i]) { ok = false; break; }
    if (!ok) {
        sentinel_kernel<<<(out_size + 255) / 256, 256, 0, stream>>>(out, out_size);
        return;
    }

    const float* x   = (const float*)d_in[0];
    const float* wq  = (const float*)d_in[1];  const float* bq  = (const float*)d_in[2];
    const float* wk  = (const float*)d_in[3];  const float* bk  = (const float*)d_in[4];
    const float* wv  = (const float*)d_in[5];  const float* bv  = (const float*)d_in[6];
    const float* wo  = (const float*)d_in[7];  const float* bo  = (const float*)d_in[8];
    const float* rel = (const float*)d_in[9];
    const float* g1  = (const float*)d_in[10]; const float* be1 = (const float*)d_in[11];
    const float* g2  = (const float*)d_in[12]; const float* be2 = (const float*)d_in[13];
    const float* w1  = (const float*)d_in[14]; const float* b1  = (const float*)d_in[15];
    const float* w2  = (const float*)d_in[16]; const float* b2  = (const float*)d_in[17];
    const float* w3  = (const float*)d_in[18]; const float* b3  = (const float*)d_in[19];
    const float* gf  = (const float*)d_in[20]; const float* bfp = (const float*)d_in[21];

    // ws (64 MiB = 8*NE shorts): [0]=Wts [1]=nx/ctx/yb [2]=Qb/x1 [3]=Kb/nx2/ly
    // [4]=Vb [5]=Vt [4..7]=hb (FF phase); bqkv floats at [6] (QKV phase only)
    constexpr size_t NE = (size_t)ROWS * Dc;   // 4M elements
    ushort* base = (ushort*)d_ws;
    ushort* Wts  = base;
    ushort* nx   = base + NE;
    ushort* Qb   = base + 2 * NE;              // Kb=Qb+NE, Vb=Qb+2NE contiguous
    ushort* Kb   = base + 3 * NE;
    ushort* Vb   = base + 4 * NE;
    ushort* Vt   = base + 5 * NE;
    float*  bqkv = (float*)(base + 6 * NE);
    ushort* ctx  = nx;
    ushort* x1   = Qb;
    ushort* nx2  = Kb;
    ushort* hb   = base + 4 * NE;              // 4NE shorts = 32MB
    ushort* yb   = nx;
    ushort* ly   = Kb;

    dim3 blk(256);
    dim3 gQKV(3072 / 128, ROWS / 64);   // (24, 64)
    dim3 gD(Dc / 128, ROWS / 64);       // (8, 64)
    dim3 gFF(DFFc / 128, ROWS / 128);   // (32, 32)
    dim3 cD(Dc / 64, Dc / 64);
    dim3 c1(DFFc / 64, Dc / 64);
    dim3 c2(Dc / 64, DFFc / 64);
    dim3 cV(Sc_ / 64, Bc * Hc);

    ln_kernel<true><<<ROWS, blk, 0, stream>>>(x, g1, be1, nx);
    wconv_kernel<<<cD, blk, 0, stream>>>(wq, Wts, Dc, Dc);
    wconv_kernel<<<cD, blk, 0, stream>>>(wk, Wts + (size_t)1024 * 1024, Dc, Dc);
    wconv_kernel<<<cD, blk, 0, stream>>>(wv, Wts + (size_t)2048 * 1024, Dc, Dc);
    bias3_kernel<<<12, blk, 0, stream>>>(bq, bk, bv, bqkv);
    gemm_bt<64, 128, ushort><<<gQKV, blk, 0, stream>>>(nx, Wts, bqkv, nullptr, nullptr, nullptr, Qb, ROWS, 3072, Dc, 0, 1);
    vconv_kernel<<<cV, blk, 0, stream>>>(Vb, Vt);
    attn_kernel<<<ROWS, blk, 0, stream>>>(Qb, Kb, Vt, rel, ctx);
    wconv_kernel<<<cD, blk, 0, stream>>>(wo, Wts, Dc, Dc);
    gemm_bt<64, 128, ushort><<<gD, blk, 0, stream>>>(ctx, Wts, bo, x, nullptr, nullptr, x1, ROWS, Dc, Dc, 0, 0);
    ln_kernel<false><<<ROWS, blk, 0, stream>>>(x1, g2, be2, nx2);
    wconv_kernel<<<c1, blk, 0, stream>>>(w1, Wts, Dc, DFFc);
    gemm_bt<128, 128, ushort><<<gFF, blk, 0, stream>>>(nx2, Wts, b1, nullptr, nullptr, nullptr, hb, ROWS, DFFc, Dc, 1, 0);
    wconv_kernel<<<c2, blk, 0, stream>>>(w2, Wts, DFFc, Dc);
    gemm_bt<64, 128, ushort><<<gD, blk, 0, stream>>>(hb, Wts, b2, nullptr, nx2, nullptr, yb, ROWS, Dc, DFFc, 0, 0);
    ln_kernel<false><<<ROWS, blk, 0, stream>>>(yb, gf, bfp, ly);
    wconv_kernel<<<cD, blk, 0, stream>>>(w3, Wts, Dc, Dc);
    gemm_bt<64, 128, float><<<gD, blk, 0, stream>>>(ly, Wts, b3, nullptr, x1, yb, out, ROWS, Dc, Dc, 0, 0);
}